// Round 4
// baseline (369.810 us; speedup 1.0000x reference)
//
#include <hip/hip_runtime.h>
#include <hip/hip_bf16.h>

#define NT 4096   // tokens
#define DM 1024   // d_model
#define DH 4096   // d_hidden
#define NE 8      // experts

#define BM 128
#define BN 128
#define BK 32
#define KT 32        // K-steps per GEMM K-window (1024 / 32)
#define MSPLIT 4     // M-slots per expert (stride loop covers the rest)
#define KSPLIT 4
#define BKP 40       // fallback-path LDS pad

typedef short bf16x8 __attribute__((ext_vector_type(8)));
typedef float f32x4 __attribute__((ext_vector_type(4)));

// ws layout (fast path) ------------------------------------------------------
#define O_COUNTS 0ull
#define O_OFF    64ull
#define O_BUCKET 256ull
#define O_XB     (O_BUCKET + (size_t)NE * NT * 4)            // 131328
#define O_H      (O_XB + (size_t)NT * DM * 2)                // +8 MB
#define O_W1T    (O_H + (size_t)NT * DH * 2)                 // +32 MB
#define O_W2T    (O_W1T + (size_t)NE * DM * DH * 2)          // +64 MB
#define WS_NEED  (O_W2T + (size_t)NE * DH * DM * 2)          // ~168 MiB
#define O_P      O_W1T  // split-K partials (4*NT*DM*4 = 64 MB) alias dead w1t

static __device__ __forceinline__ unsigned short f2bf(float f) {
  union { __hip_bfloat16 h; unsigned short u; } cv;
  cv.h = __float2bfloat16(f);
  return cv.u;
}

static __device__ __forceinline__ void gload16(const void* g, void* l) {
  __builtin_amdgcn_global_load_lds(
      (const __attribute__((address_space(1))) void*)g,
      (__attribute__((address_space(3))) void*)l, 16, 0, 0);
}

#define VMCNT4() asm volatile("s_waitcnt vmcnt(4)" ::: "memory")
#define VMCNT0() asm volatile("s_waitcnt vmcnt(0)" ::: "memory")

// ---------------------------------------------------------------------------
// Gate: one wave per token. 8 logits (double accum -> first-max argmax),
// scatter token into expert bucket, convert x row to bf16.
// ---------------------------------------------------------------------------
__global__ __launch_bounds__(256) void gate_route_kernel(
    const float* __restrict__ x, const float* __restrict__ gw,
    const float* __restrict__ gb, int* __restrict__ counts,
    int* __restrict__ bucket, __hip_bfloat16* __restrict__ xb) {
  const int wid = threadIdx.x >> 6;
  const int lane = threadIdx.x & 63;
  const int t = blockIdx.x * 4 + wid;

  const float4* xrow = (const float4*)(x + (size_t)t * DM);
  ushort4* xbrow = (ushort4*)(xb + (size_t)t * DM);

  double part[NE];
#pragma unroll
  for (int e = 0; e < NE; ++e) part[e] = 0.0;

#pragma unroll
  for (int q = 0; q < 4; ++q) {
    float4 v = xrow[q * 64 + lane];
    ushort4 s;
    s.x = f2bf(v.x); s.y = f2bf(v.y); s.z = f2bf(v.z); s.w = f2bf(v.w);
    xbrow[q * 64 + lane] = s;
#pragma unroll
    for (int e = 0; e < NE; ++e) {
      float4 w = ((const float4*)(gw + (size_t)e * DM))[q * 64 + lane];
      part[e] += (double)v.x * w.x + (double)v.y * w.y +
                 (double)v.z * w.z + (double)v.w * w.w;
    }
  }
#pragma unroll
  for (int off = 32; off; off >>= 1) {
#pragma unroll
    for (int e = 0; e < NE; ++e) part[e] += __shfl_down(part[e], off);
  }
  if (lane == 0) {
    double best = part[0] + (double)gb[0];
    int bi = 0;
#pragma unroll
    for (int e = 1; e < NE; ++e) {
      double le = part[e] + (double)gb[e];
      if (le > best) { best = le; bi = e; }
    }
    int pos = atomicAdd(&counts[bi], 1);
    bucket[bi * NT + pos] = t;
  }
}

__global__ void prefix_kernel(const int* __restrict__ counts,
                              int* __restrict__ off) {
  if (threadIdx.x == 0 && blockIdx.x == 0) {
    int r = 0;
#pragma unroll
    for (int e = 0; e < NE; ++e) { off[e] = r; r += counts[e]; }
    off[NE] = r;
  }
}

// ---------------------------------------------------------------------------
// Unified transpose-convert for BOTH weights: fp32 [E][K][N] -> bf16 [E][N][K].
// First NE*1024 blocks do w1 (K=DM,N=DH), rest do w2 (K=DH,N=DM). 64x64 tiles.
// ---------------------------------------------------------------------------
__global__ __launch_bounds__(256) void convert_both_kernel(
    const float* __restrict__ w1, const float* __restrict__ w2,
    __hip_bfloat16* __restrict__ w1t, __hip_bfloat16* __restrict__ w2t) {
  int id = blockIdx.x;
  const float* S;
  __hip_bfloat16* D;
  int N, K, n0, k0;
  if (id < NE * 1024) {
    const int e = id >> 10, rem = id & 1023;
    K = DM; N = DH;
    n0 = (rem & 63) * 64; k0 = (rem >> 6) * 64;
    S = w1 + (size_t)e * DM * DH;
    D = w1t + (size_t)e * DM * DH;
  } else {
    id -= NE * 1024;
    const int e = id >> 10, rem = id & 1023;
    K = DH; N = DM;
    n0 = (rem & 15) * 64; k0 = (rem >> 4) * 64;
    S = w2 + (size_t)e * DH * DM;
    D = w2t + (size_t)e * DH * DM;
  }
  __shared__ __align__(16) __hip_bfloat16 Ls[64][72];
  const int tid = threadIdx.x;
  const int rk = tid >> 4, c4 = tid & 15;
#pragma unroll
  for (int j = 0; j < 4; ++j) {
    const int k = rk + 16 * j;
    float4 v = *(const float4*)(S + (size_t)(k0 + k) * N + n0 + c4 * 4);
    Ls[c4 * 4 + 0][k] = __float2bfloat16(v.x);
    Ls[c4 * 4 + 1][k] = __float2bfloat16(v.y);
    Ls[c4 * 4 + 2][k] = __float2bfloat16(v.z);
    Ls[c4 * 4 + 3][k] = __float2bfloat16(v.w);
  }
  __syncthreads();
  const int rn = tid >> 2, q = tid & 3;
#pragma unroll
  for (int j = 0; j < 2; ++j) {
    const int ch = q + 4 * j;
    uint4 w = *(const uint4*)&Ls[rn][ch * 8];
    *(uint4*)(D + (size_t)(n0 + rn) * K + k0 + ch * 8) = w;
  }
}

// ---------------------------------------------------------------------------
// Counted-vmcnt 3-buffer routed GEMM (T4): 128x128 tile, BK=32, raw s_barrier,
// s_waitcnt vmcnt(4) in steady state (never 0 in-loop), gl_lds(16B) staging.
// Depth-2 prefetch: tiles kt,kt+1,kt+2 in flight. Active-only grid: each block
// owns (expert e, M-slot) and stride-loops M-tiles (mtile += MSPLIT).
// MODE 0: A = xb gathered via bucket; out = relu(acc+b1) -> h (bf16,
//         bucket-slot-order rows). MODE 1: A = h contiguous, K-window
//         kq*1024..+1024, out = fp32 partials P[kq].
// ---------------------------------------------------------------------------
template <int MODE>
__global__ __launch_bounds__(256) void moe_gemm_fast(
    const __hip_bfloat16* __restrict__ A, const __hip_bfloat16* __restrict__ B,
    const float* __restrict__ biasAll, const int* __restrict__ counts,
    const int* __restrict__ off, const int* __restrict__ bucket,
    void* __restrict__ Out, int Ktot, int N, int lda) {
  // flat id: e in low 3 bits (XCD pin), then M-slot, then (kq,)ntile
  int flat = blockIdx.x;
  const int e = flat & (NE - 1);
  int t = flat >> 3;
  const int mslot = t % MSPLIT;
  t /= MSPLIT;
  int kq, ntile;
  if (MODE == 0) { kq = 0; ntile = t; }
  else { kq = t & (KSPLIT - 1); ntile = t >> 2; }

  const int cnt = counts[e];
  const int goff = off[e];
  const int n0 = ntile * BN;
  const int kbase = kq * (DH / KSPLIT);  // 0 for MODE 0

  __shared__ __align__(16) __hip_bfloat16 As[3][BM][BK];
  __shared__ __align__(16) __hip_bfloat16 Bs[3][BN][BK];

  const int tid = threadIdx.x;
  const int lane = tid & 63;
  const int wid = tid >> 6;
  const int lr = lane >> 2, lc = lane & 3;  // 16 rows x 64 B per gl_lds inst

  const __hip_bfloat16* bP0 =
      B + ((size_t)e * N + n0 + 32 * wid + lr) * Ktot + kbase + lc * 8;
  const __hip_bfloat16* bP1 = bP0 + (size_t)16 * Ktot;

  const int wm = (wid >> 1) * 64, wn = (wid & 1) * 64;
  const int fr = lane & 15, ks = lane >> 4;

  const float* bias = (MODE == 0) ? biasAll + (size_t)e * DH : nullptr;
  __hip_bfloat16* Hout = (__hip_bfloat16*)Out;
  float* Pout = (float*)Out + (size_t)kq * NT * DM;

#define STAGE(b, kt)                                  \
  do {                                                \
    const int ko_ = (kt) * BK;                        \
    gload16(aP0 + ko_, &As[b][32 * wid][0]);          \
    gload16(aP1 + ko_, &As[b][32 * wid + 16][0]);     \
    gload16(bP0 + ko_, &Bs[b][32 * wid][0]);          \
    gload16(bP1 + ko_, &Bs[b][32 * wid + 16][0]);     \
  } while (0)

#define COMPUTE(b)                                                           \
  do {                                                                       \
    bf16x8 afr[4], bfr[4];                                                   \
    _Pragma("unroll") for (int m = 0; m < 4; ++m)                            \
        afr[m] = *(const bf16x8*)&As[b][wm + m * 16 + fr][ks * 8];           \
    _Pragma("unroll") for (int n = 0; n < 4; ++n)                            \
        bfr[n] = *(const bf16x8*)&Bs[b][wn + n * 16 + fr][ks * 8];           \
    _Pragma("unroll") for (int m = 0; m < 4; ++m)                            \
        _Pragma("unroll") for (int n = 0; n < 4; ++n)                        \
            acc[m][n] = __builtin_amdgcn_mfma_f32_16x16x32_bf16(             \
                afr[m], bfr[n], acc[m][n], 0, 0, 0);                         \
  } while (0)

  for (int mtile = mslot; mtile * BM < cnt; mtile += MSPLIT) {
    const int m0 = mtile * BM;
    const int s0 = min(m0 + 32 * wid + lr, cnt - 1);
    const int s1 = min(m0 + 32 * wid + 16 + lr, cnt - 1);
    const __hip_bfloat16 *aP0, *aP1;
    if (MODE == 0) {
      aP0 = A + (size_t)bucket[e * NT + s0] * lda + lc * 8;
      aP1 = A + (size_t)bucket[e * NT + s1] * lda + lc * 8;
    } else {
      aP0 = A + (size_t)(goff + s0) * lda + kbase + lc * 8;
      aP1 = A + (size_t)(goff + s1) * lda + kbase + lc * 8;
    }

    f32x4 acc[4][4];
#pragma unroll
    for (int m = 0; m < 4; ++m)
#pragma unroll
      for (int n = 0; n < 4; ++n) acc[m][n] = (f32x4){0.f, 0.f, 0.f, 0.f};

    // all waves done reading LDS from the previous M-tile before restaging
    __builtin_amdgcn_s_barrier();
    STAGE(0, 0);
    STAGE(1, 1);

    for (int kt = 0; kt < KT - 1; ++kt) {
      VMCNT4();  // tile kt landed (tile kt+1 [,kt+2] still in flight)
      __builtin_amdgcn_s_barrier();
      __builtin_amdgcn_sched_barrier(0);
      if (kt + 2 < KT) STAGE((kt + 2) % 3, kt + 2);
      COMPUTE(kt % 3);
    }
    VMCNT0();  // final tile (only once per M-tile)
    __builtin_amdgcn_s_barrier();
    __builtin_amdgcn_sched_barrier(0);
    COMPUTE((KT - 1) % 3);

    // epilogue: bias (+relu) and store (stores drain at next tile's vmcnt)
    if (MODE == 0) {
#pragma unroll
      for (int m = 0; m < 4; ++m)
#pragma unroll
        for (int r = 0; r < 4; ++r) {
          const int slot = m0 + wm + m * 16 + ks * 4 + r;
          if (slot < cnt) {
            __hip_bfloat16* orow = Hout + (size_t)(goff + slot) * DH;
#pragma unroll
            for (int n = 0; n < 4; ++n) {
              const int col = n0 + wn + n * 16 + fr;
              float v = acc[m][n][r] + bias[col];
              orow[col] = __float2bfloat16(v > 0.f ? v : 0.f);
            }
          }
        }
    } else {
#pragma unroll
      for (int m = 0; m < 4; ++m)
#pragma unroll
        for (int r = 0; r < 4; ++r) {
          const int slot = m0 + wm + m * 16 + ks * 4 + r;
          if (slot < cnt) {
            float* orow = Pout + (size_t)(goff + slot) * DM;
#pragma unroll
            for (int n = 0; n < 4; ++n) {
              const int col = n0 + wn + n * 16 + fr;
              orow[col] = acc[m][n][r];
            }
          }
        }
    }
  }
#undef STAGE
#undef COMPUTE
}

// ---------------------------------------------------------------------------
// Reduce split-K partials, add b2, scatter slot -> token.
// ---------------------------------------------------------------------------
__global__ __launch_bounds__(256) void reduce_out_kernel(
    const float* __restrict__ P, const float* __restrict__ b2,
    const int* __restrict__ off, const int* __restrict__ bucket,
    float* __restrict__ out) {
  const int gs = blockIdx.x;
  int e = 0;
#pragma unroll
  for (int i = 1; i < NE; ++i) e = (gs >= off[i]) ? i : e;
  const int tok = bucket[e * NT + (gs - off[e])];
  const int c = threadIdx.x * 4;
  float4 v = *(const float4*)(P + (size_t)gs * DM + c);
#pragma unroll
  for (int q = 1; q < KSPLIT; ++q) {
    float4 p = *(const float4*)(P + ((size_t)q * NT + gs) * DM + c);
    v.x += p.x; v.y += p.y; v.z += p.z; v.w += p.w;
  }
  float4 b = *(const float4*)(b2 + (size_t)e * DM + c);
  v.x += b.x; v.y += b.y; v.z += b.z; v.w += b.w;
  *(float4*)(out + (size_t)tok * DM + c) = v;
}

// ---------------------------------------------------------------------------
// Fallback (round-1 kernel) for small ws_size.
// ---------------------------------------------------------------------------
template <bool RELU_BF16>
__global__ __launch_bounds__(256, 2) void moe_gemm_fallback(
    const __hip_bfloat16* __restrict__ Aall, int lda,
    const float* __restrict__ Ball, int K, int N,
    const float* __restrict__ biasAll, const int* __restrict__ counts,
    const int* __restrict__ bucket, void* __restrict__ Out, int ldo) {
  const int e = blockIdx.z;
  const int cnt = counts[e];
  const int m0 = blockIdx.y * BM;
  if (m0 >= cnt) return;
  const int n0 = blockIdx.x * BN;

  const float* Bp = Ball + (size_t)e * K * N;
  const float* bias = biasAll + (size_t)e * N;
  const int* buck = bucket + e * NT;

  __shared__ __align__(16) __hip_bfloat16 As[2][BM][BKP];
  __shared__ __align__(16) __hip_bfloat16 Bs[2][BN][BKP];

  const int tid = threadIdx.x;
  const int lane = tid & 63;
  const int wid = tid >> 6;
  const int wm = (wid >> 1) * 64;
  const int wn = (wid & 1) * 64;
  const int fr = lane & 15;
  const int ks = lane >> 4;

  const int ar = tid >> 1;
  const int ah = tid & 1;
  const int atok = buck[min(m0 + ar, cnt - 1)];
  const __hip_bfloat16* aptr = Aall + (size_t)atok * lda + ah * 16;

  const int bc = tid & 31;
  const int bk0 = (tid >> 5) * 4;

  f32x4 acc[4][4];
#pragma unroll
  for (int m = 0; m < 4; ++m)
#pragma unroll
    for (int n = 0; n < 4; ++n) acc[m][n] = (f32x4){0.f, 0.f, 0.f, 0.f};

  const int KTf = K / BK;
  uint4 ra0, ra1;
  float rb[4][4];

  {
    const uint4* p = (const uint4*)(aptr);
    ra0 = p[0]; ra1 = p[1];
    const float* bbase = Bp + (size_t)bk0 * N + n0 + bc;
#pragma unroll
    for (int i = 0; i < 4; ++i)
#pragma unroll
      for (int j = 0; j < 4; ++j) rb[i][j] = bbase[(size_t)i * N + 32 * j];
  }
  {
    *(uint4*)&As[0][ar][ah * 16] = ra0;
    *(uint4*)&As[0][ar][ah * 16 + 8] = ra1;
#pragma unroll
    for (int j = 0; j < 4; ++j) {
      ushort4 w;
      w.x = f2bf(rb[0][j]); w.y = f2bf(rb[1][j]);
      w.z = f2bf(rb[2][j]); w.w = f2bf(rb[3][j]);
      *(ushort4*)&Bs[0][bc + 32 * j][bk0] = w;
    }
  }
  __syncthreads();

  for (int kt = 0; kt < KTf; ++kt) {
    const int buf = kt & 1;
    if (kt + 1 < KTf) {
      const uint4* p = (const uint4*)(aptr + (size_t)(kt + 1) * BK);
      ra0 = p[0]; ra1 = p[1];
      const float* bbase = Bp + (size_t)((kt + 1) * BK + bk0) * N + n0 + bc;
#pragma unroll
      for (int i = 0; i < 4; ++i)
#pragma unroll
        for (int j = 0; j < 4; ++j) rb[i][j] = bbase[(size_t)i * N + 32 * j];
    }

    bf16x8 afr[4], bfr[4];
#pragma unroll
    for (int m = 0; m < 4; ++m)
      afr[m] = *(const bf16x8*)&As[buf][wm + m * 16 + fr][ks * 8];
#pragma unroll
    for (int n = 0; n < 4; ++n)
      bfr[n] = *(const bf16x8*)&Bs[buf][wn + n * 16 + fr][ks * 8];
#pragma unroll
    for (int m = 0; m < 4; ++m)
#pragma unroll
      for (int n = 0; n < 4; ++n)
        acc[m][n] = __builtin_amdgcn_mfma_f32_16x16x32_bf16(afr[m], bfr[n],
                                                            acc[m][n], 0, 0, 0);

    __syncthreads();
    if (kt + 1 < KTf) {
      *(uint4*)&As[buf ^ 1][ar][ah * 16] = ra0;
      *(uint4*)&As[buf ^ 1][ar][ah * 16 + 8] = ra1;
#pragma unroll
      for (int j = 0; j < 4; ++j) {
        ushort4 w;
        w.x = f2bf(rb[0][j]); w.y = f2bf(rb[1][j]);
        w.z = f2bf(rb[2][j]); w.w = f2bf(rb[3][j]);
        *(ushort4*)&Bs[buf ^ 1][bc + 32 * j][bk0] = w;
      }
      __syncthreads();
    }
  }

  float* outF = (float*)Out;
  __hip_bfloat16* outB = (__hip_bfloat16*)Out;
#pragma unroll
  for (int m = 0; m < 4; ++m) {
#pragma unroll
    for (int r = 0; r < 4; ++r) {
      const int row = wm + m * 16 + ks * 4 + r;
      const int slot = m0 + row;
      if (slot < cnt) {
        const int tok = buck[slot];
#pragma unroll
        for (int n = 0; n < 4; ++n) {
          const int col = n0 + wn + n * 16 + fr;
          float v = acc[m][n][r] + bias[col];
          if (RELU_BF16) {
            v = v > 0.f ? v : 0.f;
            outB[(size_t)tok * ldo + col] = __float2bfloat16(v);
          } else {
            outF[(size_t)tok * ldo + col] = v;
          }
        }
      }
    }
  }
}

extern "C" void kernel_launch(void* const* d_in, const int* in_sizes, int n_in,
                              void* d_out, int out_size, void* d_ws,
                              size_t ws_size, hipStream_t stream) {
  const float* x = (const float*)d_in[0];
  const float* gw = (const float*)d_in[1];
  const float* gb = (const float*)d_in[2];
  const float* w1 = (const float*)d_in[3];
  const float* b1 = (const float*)d_in[4];
  const float* w2 = (const float*)d_in[5];
  const float* b2 = (const float*)d_in[6];
  (void)in_sizes; (void)n_in; (void)out_size;

  char* ws = (char*)d_ws;
  int* counts = (int*)(ws + O_COUNTS);
  int* off = (int*)(ws + O_OFF);
  int* bucket = (int*)(ws + O_BUCKET);
  __hip_bfloat16* xb = (__hip_bfloat16*)(ws + O_XB);
  __hip_bfloat16* h = (__hip_bfloat16*)(ws + O_H);

  hipMemsetAsync(ws, 0, 256, stream);
  gate_route_kernel<<<NT / 4, 256, 0, stream>>>(x, gw, gb, counts, bucket, xb);

  if (ws_size >= WS_NEED) {
    __hip_bfloat16* w1t = (__hip_bfloat16*)(ws + O_W1T);
    __hip_bfloat16* w2t = (__hip_bfloat16*)(ws + O_W2T);
    float* P = (float*)(ws + O_P);

    prefix_kernel<<<1, 64, 0, stream>>>(counts, off);
    convert_both_kernel<<<NE * 1024 * 2, 256, 0, stream>>>(w1, w2, w1t, w2t);
    moe_gemm_fast<0><<<NE * MSPLIT * (DH / BN), 256, 0, stream>>>(
        xb, w1t, b1, counts, off, bucket, (void*)h, DM, DH, DM);
    moe_gemm_fast<1><<<NE * MSPLIT * KSPLIT * (DM / BN), 256, 0, stream>>>(
        h, w2t, nullptr, counts, off, bucket, (void*)P, DH, DM, DH);
    reduce_out_kernel<<<NT, 256, 0, stream>>>(P, b2, off, bucket,
                                              (float*)d_out);
  } else {
    // small-ws fallback: round-1 path
    dim3 g1(DH / BN, NT / BM, NE);
    moe_gemm_fallback<true><<<g1, 256, 0, stream>>>(
        xb, DM, w1, DM, DH, b1, counts, bucket, (void*)h, DH);
    dim3 g2(DM / BN, NT / BM, NE);
    moe_gemm_fallback<false><<<g2, 256, 0, stream>>>(
        h, DH, w2, DH, DM, b2, counts, bucket, d_out, DM);
  }
}

// Round 5
// 332.492 us; speedup vs baseline: 1.1122x; 1.1122x over previous
//
#include <hip/hip_runtime.h>
#include <hip/hip_bf16.h>

#define NT 4096   // tokens
#define DM 1024   // d_model
#define DH 4096   // d_hidden
#define NE 8      // experts

#define BM 128
#define BN 128
#define BK 32
#define KT 32        // K-steps per GEMM K-window (1024 / 32)
#define MSPLIT 4     // M-slots per expert
#define KSPLIT 4
#define BKP 40       // B LDS row stride (elements) = 80 B (16B-aligned)

typedef short bf16x8 __attribute__((ext_vector_type(8)));
typedef float f32x4 __attribute__((ext_vector_type(4)));

// ws layout ------------------------------------------------------------------
#define O_COUNTS 0ull
#define O_OFF    64ull
#define O_BUCKET 256ull
#define O_XB     (O_BUCKET + (size_t)NE * NT * 4)
#define O_H      (O_XB + (size_t)NT * DM * 2)                // +8 MB
#define O_P      (O_H + (size_t)NT * DH * 2)                 // +32 MB
#define WS_NEED  (O_P + (size_t)KSPLIT * NT * DM * 4)        // ~104 MiB

static __device__ __forceinline__ unsigned short f2bf(float f) {
  union { __hip_bfloat16 h; unsigned short u; } cv;
  cv.h = __float2bfloat16(f);
  return cv.u;
}

static __device__ __forceinline__ void gload16(const void* g, void* l) {
  __builtin_amdgcn_global_load_lds(
      (const __attribute__((address_space(1))) void*)g,
      (__attribute__((address_space(3))) void*)l, 16, 0, 0);
}

#define VM0() asm volatile("s_waitcnt vmcnt(0)" ::: "memory")
#define VM2() asm volatile("s_waitcnt vmcnt(2)" ::: "memory")
#define VM6() asm volatile("s_waitcnt vmcnt(6)" ::: "memory")
#define LGKM0() asm volatile("s_waitcnt lgkmcnt(0)" ::: "memory")
#define BARRIER()                        \
  do {                                   \
    asm volatile("" ::: "memory");       \
    __builtin_amdgcn_s_barrier();        \
    asm volatile("" ::: "memory");       \
  } while (0)

// ---------------------------------------------------------------------------
// Gate: one wave per token. 8 logits (double accum -> first-max argmax),
// scatter token into expert bucket, convert x row to bf16.
// ---------------------------------------------------------------------------
__global__ __launch_bounds__(256) void gate_route_kernel(
    const float* __restrict__ x, const float* __restrict__ gw,
    const float* __restrict__ gb, int* __restrict__ counts,
    int* __restrict__ bucket, __hip_bfloat16* __restrict__ xb) {
  const int wid = threadIdx.x >> 6;
  const int lane = threadIdx.x & 63;
  const int t = blockIdx.x * 4 + wid;

  const float4* xrow = (const float4*)(x + (size_t)t * DM);
  ushort4* xbrow = (ushort4*)(xb + (size_t)t * DM);

  double part[NE];
#pragma unroll
  for (int e = 0; e < NE; ++e) part[e] = 0.0;

#pragma unroll
  for (int q = 0; q < 4; ++q) {
    float4 v = xrow[q * 64 + lane];
    ushort4 s;
    s.x = f2bf(v.x); s.y = f2bf(v.y); s.z = f2bf(v.z); s.w = f2bf(v.w);
    xbrow[q * 64 + lane] = s;
#pragma unroll
    for (int e = 0; e < NE; ++e) {
      float4 w = ((const float4*)(gw + (size_t)e * DM))[q * 64 + lane];
      part[e] += (double)v.x * w.x + (double)v.y * w.y +
                 (double)v.z * w.z + (double)v.w * w.w;
    }
  }
#pragma unroll
  for (int off = 32; off; off >>= 1) {
#pragma unroll
    for (int e = 0; e < NE; ++e) part[e] += __shfl_down(part[e], off);
  }
  if (lane == 0) {
    double best = part[0] + (double)gb[0];
    int bi = 0;
#pragma unroll
    for (int e = 1; e < NE; ++e) {
      double le = part[e] + (double)gb[e];
      if (le > best) { best = le; bi = e; }
    }
    int pos = atomicAdd(&counts[bi], 1);
    bucket[bi * NT + pos] = t;
  }
}

__global__ void prefix_kernel(const int* __restrict__ counts,
                              int* __restrict__ off) {
  if (threadIdx.x == 0 && blockIdx.x == 0) {
    int r = 0;
#pragma unroll
    for (int e = 0; e < NE; ++e) { off[e] = r; r += counts[e]; }
    off[NE] = r;
  }
}

// ---------------------------------------------------------------------------
// Fused-convert routed GEMM. A (bf16) staged via global_load_lds into linear
// As[2][BM][BK]. B read DIRECTLY from fp32 weights [E][K][N]: 4x float4
// per thread per tile (coalesced along n), cvt to bf16 in-reg, transposed
// ds_write_b64 into Bs[2][BN][BKP] with a 16B-group XOR swizzle
//   col(k) = ((k>>3) ^ ((n>>2)&3))*8 + (k&7)
// which keeps 8-k contiguity for the bf16x8 fragment reads and caps write
// conflicts at 8-way. Counted-vmcnt double-buffer: never vmcnt(0) in-loop.
// MODE 0: A = xb gathered via bucket; out = relu(acc+b1) -> h (bucket order).
// MODE 1: A = h contiguous rows, K-window kq*1024; out = fp32 partials P[kq].
// ---------------------------------------------------------------------------
template <int MODE>
__global__ __launch_bounds__(256, 3) void moe_gemm_fused(
    const __hip_bfloat16* __restrict__ A, const float* __restrict__ Ball,
    const float* __restrict__ biasAll, const int* __restrict__ counts,
    const int* __restrict__ off, const int* __restrict__ bucket,
    void* __restrict__ Out, int Ktot, int N, int lda) {
  // flat id: e in low 3 bits (XCD pin), then M-slot, then (kq,)ntile
  int flat = blockIdx.x;
  const int e = flat & (NE - 1);
  int t = flat >> 3;
  const int mslot = t % MSPLIT;
  t /= MSPLIT;
  int kq, ntile;
  if (MODE == 0) { kq = 0; ntile = t; }
  else { kq = t & (KSPLIT - 1); ntile = t >> 2; }

  const int cnt = counts[e];
  const int goff = off[e];
  const int n0 = ntile * BN;
  const int kbase = kq * (DH / KSPLIT);  // 0 for MODE 0

  __shared__ __align__(16) __hip_bfloat16 As[2][BM][BK];
  __shared__ __align__(16) __hip_bfloat16 Bs[2][BN][BKP];

  const int tid = threadIdx.x;
  const int lane = tid & 63;
  const int wid = tid >> 6;
  const int lr = lane >> 2, lc = lane & 3;  // A: 16 rows x 64 B per gl_lds

  // B staging geometry: thread covers k rows 4*bg..4*bg+3, cols bn0..bn0+3
  const int bt31 = tid & 31, bg = tid >> 5;
  const int bn0 = bt31 * 4;
  const int bkp0 = (((bg >> 1) ^ (bt31 & 3)) << 3) | ((bg & 1) << 2);
  const float* bTile = Ball + (size_t)e * Ktot * N +
                       (size_t)(kbase + bg * 4) * N + n0 + bn0;

  const int wm = (wid >> 1) * 64, wn = (wid & 1) * 64;
  const int fr = lane & 15, ks = lane >> 4;
  const int bks = ks ^ (fr >> 2);  // swizzled k-group for B fragment reads

  const float* bias = (MODE == 0) ? biasAll + (size_t)e * DH : nullptr;
  __hip_bfloat16* Hout = (__hip_bfloat16*)Out;
  float* Pout = (float*)Out + (size_t)kq * NT * DM;

  float4 rb0, rb1, rb2, rb3;

#define BISSUE(kt)                                        \
  do {                                                    \
    const float* bb = bTile + (size_t)(kt) * BK * N;      \
    rb0 = *(const float4*)(bb);                           \
    rb1 = *(const float4*)(bb + (size_t)N);               \
    rb2 = *(const float4*)(bb + 2 * (size_t)N);           \
    rb3 = *(const float4*)(bb + 3 * (size_t)N);           \
  } while (0)

#define BWRITE(b)                                         \
  do {                                                    \
    ushort4 w;                                            \
    w.x = f2bf(rb0.x); w.y = f2bf(rb1.x);                 \
    w.z = f2bf(rb2.x); w.w = f2bf(rb3.x);                 \
    *(ushort4*)&Bs[b][bn0 + 0][bkp0] = w;                 \
    w.x = f2bf(rb0.y); w.y = f2bf(rb1.y);                 \
    w.z = f2bf(rb2.y); w.w = f2bf(rb3.y);                 \
    *(ushort4*)&Bs[b][bn0 + 1][bkp0] = w;                 \
    w.x = f2bf(rb0.z); w.y = f2bf(rb1.z);                 \
    w.z = f2bf(rb2.z); w.w = f2bf(rb3.z);                 \
    *(ushort4*)&Bs[b][bn0 + 2][bkp0] = w;                 \
    w.x = f2bf(rb0.w); w.y = f2bf(rb1.w);                 \
    w.z = f2bf(rb2.w); w.w = f2bf(rb3.w);                 \
    *(ushort4*)&Bs[b][bn0 + 3][bkp0] = w;                 \
  } while (0)

#define ASTAGE(b, kt)                                     \
  do {                                                    \
    const size_t ko_ = (size_t)(kt) * BK;                 \
    gload16(aP0 + ko_, &As[b][32 * wid][0]);              \
    gload16(aP1 + ko_, &As[b][32 * wid + 16][0]);         \
  } while (0)

#define COMPUTE(b)                                                           \
  do {                                                                       \
    bf16x8 afr[4], bfr[4];                                                   \
    _Pragma("unroll") for (int m = 0; m < 4; ++m)                            \
        afr[m] = *(const bf16x8*)&As[b][wm + m * 16 + fr][ks * 8];           \
    _Pragma("unroll") for (int n = 0; n < 4; ++n)                            \
        bfr[n] = *(const bf16x8*)&Bs[b][wn + n * 16 + fr][bks * 8];          \
    _Pragma("unroll") for (int m = 0; m < 4; ++m)                            \
        _Pragma("unroll") for (int n = 0; n < 4; ++n)                        \
            acc[m][n] = __builtin_amdgcn_mfma_f32_16x16x32_bf16(             \
                afr[m], bfr[n], acc[m][n], 0, 0, 0);                         \
  } while (0)

  for (int mtile = mslot; mtile * BM < cnt; mtile += MSPLIT) {
    const int m0 = mtile * BM;
    const int s0 = min(m0 + 32 * wid + lr, cnt - 1);
    const int s1 = min(m0 + 32 * wid + 16 + lr, cnt - 1);
    const __hip_bfloat16 *aP0, *aP1;
    if (MODE == 0) {
      aP0 = A + (size_t)bucket[e * NT + s0] * lda + lc * 8;
      aP1 = A + (size_t)bucket[e * NT + s1] * lda + lc * 8;
    } else {
      aP0 = A + (size_t)(goff + s0) * lda + kbase + lc * 8;
      aP1 = A + (size_t)(goff + s1) * lda + kbase + lc * 8;
    }

    f32x4 acc[4][4];
#pragma unroll
    for (int m = 0; m < 4; ++m)
#pragma unroll
      for (int n = 0; n < 4; ++n) acc[m][n] = (f32x4){0.f, 0.f, 0.f, 0.f};

    // prologue ------------------------------------------------------------
    BARRIER();          // prev M-tile readers done before restaging
    BISSUE(0);          // 4 vmem
    ASTAGE(0, 0);       // 2 vmem
    VM0();              // tile 0 fully landed (also drains prior stores)
    BWRITE(0);
    BISSUE(1);          // 4 vmem in flight
    ASTAGE(1, 1);       // +2 -> 6 in flight
    LGKM0();
    BARRIER();          // Bs[0]/As[0] visible to all

    // main loop: outstanding entering iter kt = rb(kt+1)4 + A(kt+1)2 = 6
    for (int kt = 0; kt < KT; ++kt) {
      const int buf = kt & 1;
      COMPUTE(buf);
      if (kt == KT - 1) break;
      VM2();                                 // rb(kt+1) landed
      BWRITE(buf ^ 1);
      if (kt + 2 < KT) BISSUE(kt + 2);       // -> 2+4 = 6 in flight
      BARRIER();                             // all waves done reading buf
      if (kt + 2 < KT) {
        ASTAGE(buf, kt + 2);                 // -> 8 in flight
        VM6();                               // A(kt+1) landed, kt+2 flying
      } else {
        VM0();                               // drain final A
      }
      LGKM0();
      BARRIER();                             // Bs/As[buf^1] ready
    }

    // epilogue ------------------------------------------------------------
    if (MODE == 0) {
#pragma unroll
      for (int m = 0; m < 4; ++m)
#pragma unroll
        for (int r = 0; r < 4; ++r) {
          const int slot = m0 + wm + m * 16 + ks * 4 + r;
          if (slot < cnt) {
            __hip_bfloat16* orow = Hout + (size_t)(goff + slot) * DH;
#pragma unroll
            for (int n = 0; n < 4; ++n) {
              const int col = n0 + wn + n * 16 + fr;
              float v = acc[m][n][r] + bias[col];
              orow[col] = __float2bfloat16(v > 0.f ? v : 0.f);
            }
          }
        }
    } else {
#pragma unroll
      for (int m = 0; m < 4; ++m)
#pragma unroll
        for (int r = 0; r < 4; ++r) {
          const int slot = m0 + wm + m * 16 + ks * 4 + r;
          if (slot < cnt) {
            float* orow = Pout + (size_t)(goff + slot) * DM;
#pragma unroll
            for (int n = 0; n < 4; ++n) {
              const int col = n0 + wn + n * 16 + fr;
              orow[col] = acc[m][n][r];
            }
          }
        }
    }
  }
#undef BISSUE
#undef BWRITE
#undef ASTAGE
#undef COMPUTE
}

// ---------------------------------------------------------------------------
// Reduce split-K partials, add b2, scatter slot -> token.
// ---------------------------------------------------------------------------
__global__ __launch_bounds__(256) void reduce_out_kernel(
    const float* __restrict__ P, const float* __restrict__ b2,
    const int* __restrict__ off, const int* __restrict__ bucket,
    float* __restrict__ out) {
  const int gs = blockIdx.x;
  int e = 0;
#pragma unroll
  for (int i = 1; i < NE; ++i) e = (gs >= off[i]) ? i : e;
  const int tok = bucket[e * NT + (gs - off[e])];
  const int c = threadIdx.x * 4;
  float4 v = *(const float4*)(P + (size_t)gs * DM + c);
#pragma unroll
  for (int q = 1; q < KSPLIT; ++q) {
    float4 p = *(const float4*)(P + ((size_t)q * NT + gs) * DM + c);
    v.x += p.x; v.y += p.y; v.z += p.z; v.w += p.w;
  }
  float4 b = *(const float4*)(b2 + (size_t)e * DM + c);
  v.x += b.x; v.y += b.y; v.z += b.z; v.w += b.w;
  *(float4*)(out + (size_t)tok * DM + c) = v;
}

// ---------------------------------------------------------------------------
// Fallback for small ws (fp32-B, fused, h in token order).
// ---------------------------------------------------------------------------
template <bool RELU_BF16>
__global__ __launch_bounds__(256, 2) void moe_gemm_fallback(
    const __hip_bfloat16* __restrict__ Aall, int lda,
    const float* __restrict__ Ball, int K, int N,
    const float* __restrict__ biasAll, const int* __restrict__ counts,
    const int* __restrict__ bucket, void* __restrict__ Out, int ldo) {
  const int e = blockIdx.z;
  const int cnt = counts[e];
  const int m0 = blockIdx.y * BM;
  if (m0 >= cnt) return;
  const int n0 = blockIdx.x * BN;

  const float* Bp = Ball + (size_t)e * K * N;
  const float* bias = biasAll + (size_t)e * N;
  const int* buck = bucket + e * NT;

  __shared__ __align__(16) __hip_bfloat16 As[2][BM][BKP];
  __shared__ __align__(16) __hip_bfloat16 Bs[2][BN][BKP];

  const int tid = threadIdx.x;
  const int lane = tid & 63;
  const int wid = tid >> 6;
  const int wm = (wid >> 1) * 64;
  const int wn = (wid & 1) * 64;
  const int fr = lane & 15;
  const int ks = lane >> 4;

  const int ar = tid >> 1;
  const int ah = tid & 1;
  const int atok = buck[min(m0 + ar, cnt - 1)];
  const __hip_bfloat16* aptr = Aall + (size_t)atok * lda + ah * 16;

  const int bc = tid & 31;
  const int bk0 = (tid >> 5) * 4;

  f32x4 acc[4][4];
#pragma unroll
  for (int m = 0; m < 4; ++m)
#pragma unroll
    for (int n = 0; n < 4; ++n) acc[m][n] = (f32x4){0.f, 0.f, 0.f, 0.f};

  const int KTf = K / BK;
  uint4 ra0, ra1;
  float rb[4][4];

  {
    const uint4* p = (const uint4*)(aptr);
    ra0 = p[0]; ra1 = p[1];
    const float* bbase = Bp + (size_t)bk0 * N + n0 + bc;
#pragma unroll
    for (int i = 0; i < 4; ++i)
#pragma unroll
      for (int j = 0; j < 4; ++j) rb[i][j] = bbase[(size_t)i * N + 32 * j];
  }
  {
    *(uint4*)&As[0][ar][ah * 16] = ra0;
    *(uint4*)&As[0][ar][ah * 16 + 8] = ra1;
#pragma unroll
    for (int j = 0; j < 4; ++j) {
      ushort4 w;
      w.x = f2bf(rb[0][j]); w.y = f2bf(rb[1][j]);
      w.z = f2bf(rb[2][j]); w.w = f2bf(rb[3][j]);
      *(ushort4*)&Bs[0][bc + 32 * j][bk0] = w;
    }
  }
  __syncthreads();

  for (int kt = 0; kt < KTf; ++kt) {
    const int buf = kt & 1;
    if (kt + 1 < KTf) {
      const uint4* p = (const uint4*)(aptr + (size_t)(kt + 1) * BK);
      ra0 = p[0]; ra1 = p[1];
      const float* bbase = Bp + (size_t)((kt + 1) * BK + bk0) * N + n0 + bc;
#pragma unroll
      for (int i = 0; i < 4; ++i)
#pragma unroll
        for (int j = 0; j < 4; ++j) rb[i][j] = bbase[(size_t)i * N + 32 * j];
    }

    bf16x8 afr[4], bfr[4];
#pragma unroll
    for (int m = 0; m < 4; ++m)
      afr[m] = *(const bf16x8*)&As[buf][wm + m * 16 + fr][ks * 8];
#pragma unroll
    for (int n = 0; n < 4; ++n)
      bfr[n] = *(const bf16x8*)&Bs[buf][wn + n * 16 + fr][ks * 8];
#pragma unroll
    for (int m = 0; m < 4; ++m)
#pragma unroll
      for (int n = 0; n < 4; ++n)
        acc[m][n] = __builtin_amdgcn_mfma_f32_16x16x32_bf16(afr[m], bfr[n],
                                                            acc[m][n], 0, 0, 0);

    __syncthreads();
    if (kt + 1 < KTf) {
      *(uint4*)&As[buf ^ 1][ar][ah * 16] = ra0;
      *(uint4*)&As[buf ^ 1][ar][ah * 16 + 8] = ra1;
#pragma unroll
      for (int j = 0; j < 4; ++j) {
        ushort4 w;
        w.x = f2bf(rb[0][j]); w.y = f2bf(rb[1][j]);
        w.z = f2bf(rb[2][j]); w.w = f2bf(rb[3][j]);
        *(ushort4*)&Bs[buf ^ 1][bc + 32 * j][bk0] = w;
      }
      __syncthreads();
    }
  }

  float* outF = (float*)Out;
  __hip_bfloat16* outB = (__hip_bfloat16*)Out;
#pragma unroll
  for (int m = 0; m < 4; ++m) {
#pragma unroll
    for (int r = 0; r < 4; ++r) {
      const int row = wm + m * 16 + ks * 4 + r;
      const int slot = m0 + row;
      if (slot < cnt) {
        const int tok = buck[slot];
#pragma unroll
        for (int n = 0; n < 4; ++n) {
          const int col = n0 + wn + n * 16 + fr;
          float v = acc[m][n][r] + bias[col];
          if (RELU_BF16) {
            v = v > 0.f ? v : 0.f;
            outB[(size_t)tok * ldo + col] = __float2bfloat16(v);
          } else {
            outF[(size_t)tok * ldo + col] = v;
          }
        }
      }
    }
  }
}

extern "C" void kernel_launch(void* const* d_in, const int* in_sizes, int n_in,
                              void* d_out, int out_size, void* d_ws,
                              size_t ws_size, hipStream_t stream) {
  const float* x = (const float*)d_in[0];
  const float* gw = (const float*)d_in[1];
  const float* gb = (const float*)d_in[2];
  const float* w1 = (const float*)d_in[3];
  const float* b1 = (const float*)d_in[4];
  const float* w2 = (const float*)d_in[5];
  const float* b2 = (const float*)d_in[6];
  (void)in_sizes; (void)n_in; (void)out_size;

  char* ws = (char*)d_ws;
  int* counts = (int*)(ws + O_COUNTS);
  int* off = (int*)(ws + O_OFF);
  int* bucket = (int*)(ws + O_BUCKET);
  __hip_bfloat16* xb = (__hip_bfloat16*)(ws + O_XB);
  __hip_bfloat16* h = (__hip_bfloat16*)(ws + O_H);
  float* P = (float*)(ws + O_P);

  hipMemsetAsync(ws, 0, 256, stream);
  gate_route_kernel<<<NT / 4, 256, 0, stream>>>(x, gw, gb, counts, bucket, xb);

  if (ws_size >= WS_NEED) {
    prefix_kernel<<<1, 64, 0, stream>>>(counts, off);
    moe_gemm_fused<0><<<NE * MSPLIT * (DH / BN), 256, 0, stream>>>(
        xb, w1, b1, counts, off, bucket, (void*)h, DM, DH, DM);
    moe_gemm_fused<1><<<NE * MSPLIT * KSPLIT * (DM / BN), 256, 0, stream>>>(
        h, w2, nullptr, counts, off, bucket, (void*)P, DH, DM, DH);
    reduce_out_kernel<<<NT, 256, 0, stream>>>(P, b2, off, bucket,
                                              (float*)d_out);
  } else {
    dim3 g1(DH / BN, NT / BM, NE);
    moe_gemm_fallback<true><<<g1, 256, 0, stream>>>(
        xb, DM, w1, DM, DH, b1, counts, bucket, (void*)h, DH);
    dim3 g2(DM / BN, NT / BM, NE);
    moe_gemm_fallback<false><<<g2, 256, 0, stream>>>(
        h, DH, w2, DH, DM, b2, counts, bucket, d_out, DM);
  }
}

// Round 6
// 327.898 us; speedup vs baseline: 1.1278x; 1.0140x over previous
//
#include <hip/hip_runtime.h>
#include <hip/hip_bf16.h>

#define NT 4096   // tokens
#define DM 1024   // d_model
#define DH 4096   // d_hidden
#define NE 8      // experts

#define BM 128
#define BN 128
#define BK 32
#define MAXT 36      // max padded M-tiles (32 ideal + 8 expert pad - slack)
#define MAXROWS 5120 // max padded slot rows (4096 + 8*127 = 5112, rounded)
#define KSPL2 2      // split-K for GEMM2 (K-window 2048)
#define BKP 40       // fallback LDS pad

typedef short bf16x8 __attribute__((ext_vector_type(8)));
typedef float f32x4 __attribute__((ext_vector_type(4)));

// meta ints at ws base: counts@0, poff@16, ntiles@32, tileE@48, tileRow@112,
// tileS0@176  (bucket starts at byte 1024)
#define MI_COUNTS 0
#define MI_POFF   16
#define MI_NTILES 32
#define MI_TILEE  48
#define MI_TILER  112
#define MI_TILES0 176

#define O_BUCKET 1024ull
#define O_XB  (O_BUCKET + (size_t)NE * NT * 4)                 // 132096
#define O_H   (O_XB + (size_t)NT * DM * 2)                     // +8 MB
#define O_W1T (O_H + (size_t)MAXROWS * DH * 2)                 // +40 MB
#define O_W2T (O_W1T + (size_t)NE * DM * DH * 2)               // +64 MB
#define WS_NEED (O_W2T + (size_t)NE * DH * DM * 2)             // ~176 MiB
#define O_P   O_W1T   // split-K partials (2*MAXROWS*DM*4 = 40MB) alias w1t

static __device__ __forceinline__ unsigned short f2bf(float f) {
  union { __hip_bfloat16 h; unsigned short u; } cv;
  cv.h = __float2bfloat16(f);
  return cv.u;
}

static __device__ __forceinline__ void gload16(const void* g, void* l) {
  __builtin_amdgcn_global_load_lds(
      (const __attribute__((address_space(1))) void*)g,
      (__attribute__((address_space(3))) void*)l, 16, 0, 0);
}

// ---------------------------------------------------------------------------
// Gate: one wave per token. 8 logits (double accum -> first-max argmax),
// scatter token into expert bucket, convert x row to bf16.
// ---------------------------------------------------------------------------
__global__ __launch_bounds__(256) void gate_route_kernel(
    const float* __restrict__ x, const float* __restrict__ gw,
    const float* __restrict__ gb, int* __restrict__ counts,
    int* __restrict__ bucket, __hip_bfloat16* __restrict__ xb) {
  const int wid = threadIdx.x >> 6;
  const int lane = threadIdx.x & 63;
  const int t = blockIdx.x * 4 + wid;

  const float4* xrow = (const float4*)(x + (size_t)t * DM);
  ushort4* xbrow = (ushort4*)(xb + (size_t)t * DM);

  double part[NE];
#pragma unroll
  for (int e = 0; e < NE; ++e) part[e] = 0.0;

#pragma unroll
  for (int q = 0; q < 4; ++q) {
    float4 v = xrow[q * 64 + lane];
    ushort4 s;
    s.x = f2bf(v.x); s.y = f2bf(v.y); s.z = f2bf(v.z); s.w = f2bf(v.w);
    xbrow[q * 64 + lane] = s;
#pragma unroll
    for (int e = 0; e < NE; ++e) {
      float4 w = ((const float4*)(gw + (size_t)e * DM))[q * 64 + lane];
      part[e] += (double)v.x * w.x + (double)v.y * w.y +
                 (double)v.z * w.z + (double)v.w * w.w;
    }
  }
#pragma unroll
  for (int off = 32; off; off >>= 1) {
#pragma unroll
    for (int e = 0; e < NE; ++e) part[e] += __shfl_down(part[e], off);
  }
  if (lane == 0) {
    double best = part[0] + (double)gb[0];
    int bi = 0;
#pragma unroll
    for (int e = 1; e < NE; ++e) {
      double le = part[e] + (double)gb[e];
      if (le > best) { best = le; bi = e; }
    }
    int pos = atomicAdd(&counts[bi], 1);
    bucket[bi * NT + pos] = t;
  }
}

// ---------------------------------------------------------------------------
// Prefix + padded tile table + bucket padding.
// ---------------------------------------------------------------------------
__global__ void prefix_kernel(int* __restrict__ meta, int* __restrict__ bucket) {
  if (threadIdx.x == 0) {
    int r = 0, nt = 0;
    for (int e = 0; e < NE; ++e) {
      meta[MI_POFF + e] = r;
      const int cnt = meta[MI_COUNTS + e];
      const int T = (cnt + BM - 1) / BM;
      for (int j = 0; j < T; ++j) {
        meta[MI_TILEE + nt] = e;
        meta[MI_TILER + nt] = r + j * BM;
        meta[MI_TILES0 + nt] = j * BM;
        ++nt;
      }
      r += T * BM;
    }
    meta[MI_POFF + NE] = r;
    meta[MI_NTILES] = nt;
  }
  __syncthreads();
  // pad bucket: duplicate last real token up to the tile boundary
  for (int e = 0; e < NE; ++e) {
    const int cnt = meta[MI_COUNTS + e];
    if (cnt == 0) continue;
    const int padTo = ((cnt + BM - 1) / BM) * BM;
    const int last = bucket[e * NT + cnt - 1];
    for (int i = cnt + threadIdx.x; i < padTo; i += blockDim.x)
      bucket[e * NT + i] = last;
  }
}

// ---------------------------------------------------------------------------
// Unified transpose-convert: fp32 [E][K][N] -> bf16 [E][N][K], both weights.
// ---------------------------------------------------------------------------
__global__ __launch_bounds__(256) void convert_both_kernel(
    const float* __restrict__ w1, const float* __restrict__ w2,
    __hip_bfloat16* __restrict__ w1t, __hip_bfloat16* __restrict__ w2t) {
  int id = blockIdx.x;
  const float* S;
  __hip_bfloat16* D;
  int N, K, n0, k0;
  if (id < NE * 1024) {
    const int e = id >> 10, rem = id & 1023;
    K = DM; N = DH;
    n0 = (rem & 63) * 64; k0 = (rem >> 6) * 64;
    S = w1 + (size_t)e * DM * DH;
    D = w1t + (size_t)e * DM * DH;
  } else {
    id -= NE * 1024;
    const int e = id >> 10, rem = id & 1023;
    K = DH; N = DM;
    n0 = (rem & 15) * 64; k0 = (rem >> 4) * 64;
    S = w2 + (size_t)e * DH * DM;
    D = w2t + (size_t)e * DH * DM;
  }
  __shared__ __align__(16) __hip_bfloat16 Ls[64][72];
  const int tid = threadIdx.x;
  const int rk = tid >> 4, c4 = tid & 15;
#pragma unroll
  for (int j = 0; j < 4; ++j) {
    const int k = rk + 16 * j;
    float4 v = *(const float4*)(S + (size_t)(k0 + k) * N + n0 + c4 * 4);
    Ls[c4 * 4 + 0][k] = __float2bfloat16(v.x);
    Ls[c4 * 4 + 1][k] = __float2bfloat16(v.y);
    Ls[c4 * 4 + 2][k] = __float2bfloat16(v.z);
    Ls[c4 * 4 + 3][k] = __float2bfloat16(v.w);
  }
  __syncthreads();
  const int rn = tid >> 2, q = tid & 3;
#pragma unroll
  for (int j = 0; j < 2; ++j) {
    const int ch = q + 4 * j;
    uint4 w = *(const uint4*)&Ls[rn][ch * 8];
    *(uint4*)(D + (size_t)(n0 + rn) * K + k0 + ch * 8) = w;
  }
}

// ---------------------------------------------------------------------------
// Uniform padded-tile routed GEMM: every block = one real 128x128 tile.
// 2-phase loop (STAGE next tile before COMPUTE, one barrier), gl_lds(16B),
// LDS 32KB -> 5 blocks/CU, whole grid co-resident.
// MODE 0: A = xb gathered via padded bucket; out = relu(acc+b1) -> h rows
//         row0+r (padded order). K = DM, 32 steps.
// MODE 1: A = h rows (contiguous), K-window kq*2048 (+2048), out = fp32
//         partials P[kq]. 64 steps.
// ---------------------------------------------------------------------------
template <int MODE>
__global__ __launch_bounds__(256, 5) void moe_gemm_u(
    const __hip_bfloat16* __restrict__ A, const __hip_bfloat16* __restrict__ B,
    const float* __restrict__ biasAll, const int* __restrict__ meta,
    const int* __restrict__ bucket, void* __restrict__ Out) {
  const int flat = blockIdx.x;
  const int tile = flat % MAXT;
  if (tile >= meta[MI_NTILES]) return;
  int kq, ntile;
  if (MODE == 0) { kq = 0; ntile = flat / MAXT; }
  else { const int r = flat / MAXT; kq = r & 1; ntile = r >> 1; }

  const int e = meta[MI_TILEE + tile];
  const int row0 = meta[MI_TILER + tile];   // padded global row base
  const int s0 = meta[MI_TILES0 + tile];    // slot base within expert
  const int n0 = ntile * BN;
  const int Ktot = (MODE == 0) ? DM : DH;
  const int N = (MODE == 0) ? DH : DM;
  const int KTM = (MODE == 0) ? 32 : 64;
  const int kbase = (MODE == 0) ? 0 : kq * (DH / KSPL2);

  __shared__ __align__(16) __hip_bfloat16 As[2][BM][BK];
  __shared__ __align__(16) __hip_bfloat16 Bs[2][BN][BK];

  const int tid = threadIdx.x;
  const int lane = tid & 63;
  const int wid = tid >> 6;
  const int lr = lane >> 2, lc = lane & 3;  // 16 rows x 64 B per gl_lds inst

  const __hip_bfloat16 *aP0, *aP1;
  if (MODE == 0) {
    aP0 = A + (size_t)bucket[e * NT + s0 + 32 * wid + lr] * DM + lc * 8;
    aP1 = A + (size_t)bucket[e * NT + s0 + 32 * wid + 16 + lr] * DM + lc * 8;
  } else {
    aP0 = A + (size_t)(row0 + 32 * wid + lr) * DH + kbase + lc * 8;
    aP1 = A + (size_t)(row0 + 32 * wid + 16 + lr) * DH + kbase + lc * 8;
  }
  const __hip_bfloat16* bP0 =
      B + ((size_t)e * N + n0 + 32 * wid + lr) * Ktot + kbase + lc * 8;
  const __hip_bfloat16* bP1 = bP0 + (size_t)16 * Ktot;

  const int wm = (wid >> 1) * 64, wn = (wid & 1) * 64;
  const int fr = lane & 15, ks = lane >> 4;

  f32x4 acc[4][4];
#pragma unroll
  for (int m = 0; m < 4; ++m)
#pragma unroll
    for (int n = 0; n < 4; ++n) acc[m][n] = (f32x4){0.f, 0.f, 0.f, 0.f};

#define STAGE(b, kt)                                  \
  do {                                                \
    const size_t ko_ = (size_t)(kt) * BK;             \
    gload16(aP0 + ko_, &As[b][32 * wid][0]);          \
    gload16(aP1 + ko_, &As[b][32 * wid + 16][0]);     \
    gload16(bP0 + ko_, &Bs[b][32 * wid][0]);          \
    gload16(bP1 + ko_, &Bs[b][32 * wid + 16][0]);     \
  } while (0)

  STAGE(0, 0);
  __syncthreads();

  for (int kt = 0; kt < KTM; ++kt) {
    const int buf = kt & 1;
    if (kt + 1 < KTM) STAGE(buf ^ 1, kt + 1);  // loads fly under the MFMAs
    bf16x8 afr[4], bfr[4];
#pragma unroll
    for (int m = 0; m < 4; ++m)
      afr[m] = *(const bf16x8*)&As[buf][wm + m * 16 + fr][ks * 8];
#pragma unroll
    for (int n = 0; n < 4; ++n)
      bfr[n] = *(const bf16x8*)&Bs[buf][wn + n * 16 + fr][ks * 8];
#pragma unroll
    for (int m = 0; m < 4; ++m)
#pragma unroll
      for (int n = 0; n < 4; ++n)
        acc[m][n] = __builtin_amdgcn_mfma_f32_16x16x32_bf16(afr[m], bfr[n],
                                                            acc[m][n], 0, 0, 0);
    __syncthreads();
  }
#undef STAGE

  if (MODE == 0) {
    const float* bias = biasAll + (size_t)e * DH;
    __hip_bfloat16* Hout = (__hip_bfloat16*)Out;
#pragma unroll
    for (int m = 0; m < 4; ++m)
#pragma unroll
      for (int r = 0; r < 4; ++r) {
        const int row = wm + m * 16 + ks * 4 + r;
        __hip_bfloat16* orow = Hout + (size_t)(row0 + row) * DH;
#pragma unroll
        for (int n = 0; n < 4; ++n) {
          const int col = n0 + wn + n * 16 + fr;
          float v = acc[m][n][r] + bias[col];
          orow[col] = __float2bfloat16(v > 0.f ? v : 0.f);
        }
      }
  } else {
    float* Pout = (float*)Out + (size_t)kq * MAXROWS * DM;
#pragma unroll
    for (int m = 0; m < 4; ++m)
#pragma unroll
      for (int r = 0; r < 4; ++r) {
        const int row = wm + m * 16 + ks * 4 + r;
        float* orow = Pout + (size_t)(row0 + row) * DM;
#pragma unroll
        for (int n = 0; n < 4; ++n) {
          const int col = n0 + wn + n * 16 + fr;
          orow[col] = acc[m][n][r];
        }
      }
  }
}

// ---------------------------------------------------------------------------
// Reduce split-K partials, add b2, scatter padded-row -> token.
// ---------------------------------------------------------------------------
__global__ __launch_bounds__(256) void reduce_out_kernel(
    const float* __restrict__ P, const float* __restrict__ b2,
    const int* __restrict__ meta, const int* __restrict__ bucket,
    float* __restrict__ out) {
  const int gs = blockIdx.x;
  if (gs >= meta[MI_POFF + NE]) return;
  int e = 0;
#pragma unroll
  for (int i = 1; i < NE; ++i) e = (gs >= meta[MI_POFF + i]) ? i : e;
  const int i = gs - meta[MI_POFF + e];
  if (i >= meta[MI_COUNTS + e]) return;  // pad row
  const int tok = bucket[e * NT + i];
  const int c = threadIdx.x * 4;
  float4 v = *(const float4*)(P + (size_t)gs * DM + c);
#pragma unroll
  for (int q = 1; q < KSPL2; ++q) {
    float4 p = *(const float4*)(P + ((size_t)q * MAXROWS + gs) * DM + c);
    v.x += p.x; v.y += p.y; v.z += p.z; v.w += p.w;
  }
  float4 b = *(const float4*)(b2 + (size_t)e * DM + c);
  v.x += b.x; v.y += b.y; v.z += b.z; v.w += b.w;
  *(float4*)(out + (size_t)tok * DM + c) = v;
}

// ---------------------------------------------------------------------------
// Fallback for small ws (fp32-B fused, h in token order) — round-1 proven.
// ---------------------------------------------------------------------------
template <bool RELU_BF16>
__global__ __launch_bounds__(256, 2) void moe_gemm_fallback(
    const __hip_bfloat16* __restrict__ Aall, int lda,
    const float* __restrict__ Ball, int K, int N,
    const float* __restrict__ biasAll, const int* __restrict__ counts,
    const int* __restrict__ bucket, void* __restrict__ Out, int ldo) {
  const int e = blockIdx.z;
  const int cnt = counts[e];
  const int m0 = blockIdx.y * BM;
  if (m0 >= cnt) return;
  const int n0 = blockIdx.x * BN;

  const float* Bp = Ball + (size_t)e * K * N;
  const float* bias = biasAll + (size_t)e * N;
  const int* buck = bucket + e * NT;

  __shared__ __align__(16) __hip_bfloat16 As[2][BM][BKP];
  __shared__ __align__(16) __hip_bfloat16 Bs[2][BN][BKP];

  const int tid = threadIdx.x;
  const int lane = tid & 63;
  const int wid = tid >> 6;
  const int wm = (wid >> 1) * 64;
  const int wn = (wid & 1) * 64;
  const int fr = lane & 15;
  const int ks = lane >> 4;

  const int ar = tid >> 1;
  const int ah = tid & 1;
  const int atok = buck[min(m0 + ar, cnt - 1)];
  const __hip_bfloat16* aptr = Aall + (size_t)atok * lda + ah * 16;

  const int bc = tid & 31;
  const int bk0 = (tid >> 5) * 4;

  f32x4 acc[4][4];
#pragma unroll
  for (int m = 0; m < 4; ++m)
#pragma unroll
    for (int n = 0; n < 4; ++n) acc[m][n] = (f32x4){0.f, 0.f, 0.f, 0.f};

  const int KTf = K / BK;
  uint4 ra0, ra1;
  float rb[4][4];

  {
    const uint4* p = (const uint4*)(aptr);
    ra0 = p[0]; ra1 = p[1];
    const float* bbase = Bp + (size_t)bk0 * N + n0 + bc;
#pragma unroll
    for (int i = 0; i < 4; ++i)
#pragma unroll
      for (int j = 0; j < 4; ++j) rb[i][j] = bbase[(size_t)i * N + 32 * j];
  }
  {
    *(uint4*)&As[0][ar][ah * 16] = ra0;
    *(uint4*)&As[0][ar][ah * 16 + 8] = ra1;
#pragma unroll
    for (int j = 0; j < 4; ++j) {
      ushort4 w;
      w.x = f2bf(rb[0][j]); w.y = f2bf(rb[1][j]);
      w.z = f2bf(rb[2][j]); w.w = f2bf(rb[3][j]);
      *(ushort4*)&Bs[0][bc + 32 * j][bk0] = w;
    }
  }
  __syncthreads();

  for (int kt = 0; kt < KTf; ++kt) {
    const int buf = kt & 1;
    if (kt + 1 < KTf) {
      const uint4* p = (const uint4*)(aptr + (size_t)(kt + 1) * BK);
      ra0 = p[0]; ra1 = p[1];
      const float* bbase = Bp + (size_t)((kt + 1) * BK + bk0) * N + n0 + bc;
#pragma unroll
      for (int i = 0; i < 4; ++i)
#pragma unroll
        for (int j = 0; j < 4; ++j) rb[i][j] = bbase[(size_t)i * N + 32 * j];
    }

    bf16x8 afr[4], bfr[4];
#pragma unroll
    for (int m = 0; m < 4; ++m)
      afr[m] = *(const bf16x8*)&As[buf][wm + m * 16 + fr][ks * 8];
#pragma unroll
    for (int n = 0; n < 4; ++n)
      bfr[n] = *(const bf16x8*)&Bs[buf][wn + n * 16 + fr][ks * 8];
#pragma unroll
    for (int m = 0; m < 4; ++m)
#pragma unroll
      for (int n = 0; n < 4; ++n)
        acc[m][n] = __builtin_amdgcn_mfma_f32_16x16x32_bf16(afr[m], bfr[n],
                                                            acc[m][n], 0, 0, 0);

    __syncthreads();
    if (kt + 1 < KTf) {
      *(uint4*)&As[buf ^ 1][ar][ah * 16] = ra0;
      *(uint4*)&As[buf ^ 1][ar][ah * 16 + 8] = ra1;
#pragma unroll
      for (int j = 0; j < 4; ++j) {
        ushort4 w;
        w.x = f2bf(rb[0][j]); w.y = f2bf(rb[1][j]);
        w.z = f2bf(rb[2][j]); w.w = f2bf(rb[3][j]);
        *(ushort4*)&Bs[buf ^ 1][bc + 32 * j][bk0] = w;
      }
      __syncthreads();
    }
  }

  float* outF = (float*)Out;
  __hip_bfloat16* outB = (__hip_bfloat16*)Out;
#pragma unroll
  for (int m = 0; m < 4; ++m) {
#pragma unroll
    for (int r = 0; r < 4; ++r) {
      const int row = wm + m * 16 + ks * 4 + r;
      const int slot = m0 + row;
      if (slot < cnt) {
        const int tok = buck[slot];
#pragma unroll
        for (int n = 0; n < 4; ++n) {
          const int col = n0 + wn + n * 16 + fr;
          float v = acc[m][n][r] + bias[col];
          if (RELU_BF16) {
            v = v > 0.f ? v : 0.f;
            outB[(size_t)tok * ldo + col] = __float2bfloat16(v);
          } else {
            outF[(size_t)tok * ldo + col] = v;
          }
        }
      }
    }
  }
}

extern "C" void kernel_launch(void* const* d_in, const int* in_sizes, int n_in,
                              void* d_out, int out_size, void* d_ws,
                              size_t ws_size, hipStream_t stream) {
  const float* x = (const float*)d_in[0];
  const float* gw = (const float*)d_in[1];
  const float* gb = (const float*)d_in[2];
  const float* w1 = (const float*)d_in[3];
  const float* b1 = (const float*)d_in[4];
  const float* w2 = (const float*)d_in[5];
  const float* b2 = (const float*)d_in[6];
  (void)in_sizes; (void)n_in; (void)out_size;

  char* ws = (char*)d_ws;
  int* meta = (int*)ws;
  int* counts = meta + MI_COUNTS;
  int* bucket = (int*)(ws + O_BUCKET);
  __hip_bfloat16* xb = (__hip_bfloat16*)(ws + O_XB);
  __hip_bfloat16* h = (__hip_bfloat16*)(ws + O_H);

  hipMemsetAsync(ws, 0, 1024, stream);
  gate_route_kernel<<<NT / 4, 256, 0, stream>>>(x, gw, gb, counts, bucket, xb);

  if (ws_size >= WS_NEED) {
    __hip_bfloat16* w1t = (__hip_bfloat16*)(ws + O_W1T);
    __hip_bfloat16* w2t = (__hip_bfloat16*)(ws + O_W2T);
    float* P = (float*)(ws + O_P);

    prefix_kernel<<<1, 256, 0, stream>>>(meta, bucket);
    convert_both_kernel<<<NE * 1024 * 2, 256, 0, stream>>>(w1, w2, w1t, w2t);
    moe_gemm_u<0><<<MAXT * (DH / BN), 256, 0, stream>>>(
        xb, w1t, b1, meta, bucket, (void*)h);
    moe_gemm_u<1><<<MAXT * (DM / BN) * KSPL2, 256, 0, stream>>>(
        h, w2t, nullptr, meta, bucket, (void*)P);
    reduce_out_kernel<<<MAXROWS, 256, 0, stream>>>(P, b2, meta, bucket,
                                                   (float*)d_out);
  } else {
    dim3 g1(DH / BN, NT / BM, NE);
    moe_gemm_fallback<true><<<g1, 256, 0, stream>>>(
        xb, DM, w1, DM, DH, b1, counts, bucket, (void*)h, DH);
    dim3 g2(DM / BN, NT / BM, NE);
    moe_gemm_fallback<false><<<g2, 256, 0, stream>>>(
        h, DH, w2, DH, DM, b2, counts, bucket, d_out, DM);
  }
}

// Round 7
// 280.774 us; speedup vs baseline: 1.3171x; 1.1678x over previous
//
#include <hip/hip_runtime.h>
#include <hip/hip_bf16.h>

#define NT 4096   // tokens
#define DM 1024   // d_model
#define DH 4096   // d_hidden
#define NE 8      // experts

#define BM 128
#define BN 128
#define BK 32
#define MAXT 40      // max padded M-tiles (8 experts x max 5 tiles)
#define MAXROWS 5120 // 40*128
#define KSPL2 2      // split-K for GEMM2 (K-window 2048)
#define BKP 40       // fallback LDS pad

typedef short bf16x8 __attribute__((ext_vector_type(8)));
typedef float f32x4 __attribute__((ext_vector_type(4)));
typedef float f4 __attribute__((ext_vector_type(4)));

// meta ints at ws base: counts@0, poff@16, ntiles@32, tileE@48, tileRow@112,
// tileS0@176  (bucket starts at byte 1024)
#define MI_COUNTS 0
#define MI_POFF   16
#define MI_NTILES 32
#define MI_TILEE  48
#define MI_TILER  112
#define MI_TILES0 176

#define O_BUCKET 1024ull
#define O_XB  (O_BUCKET + (size_t)NE * NT * 4)                 // 132096
#define O_H   (O_XB + (size_t)NT * DM * 2)                     // +8 MB
#define O_W1T (O_H + (size_t)MAXROWS * DH * 2)                 // +40 MB
#define O_W2T (O_W1T + (size_t)NE * DM * DH * 2)               // +64 MB
#define WS_NEED (O_W2T + (size_t)NE * DH * DM * 2)             // ~176 MiB
#define O_P   O_W1T   // split-K partials (2*MAXROWS*DM*4 = 40MB) alias w1t

static __device__ __forceinline__ unsigned short f2bf(float f) {
  union { __hip_bfloat16 h; unsigned short u; } cv;
  cv.h = __float2bfloat16(f);
  return cv.u;
}

static __device__ __forceinline__ void gload16(const void* g, void* l) {
  __builtin_amdgcn_global_load_lds(
      (const __attribute__((address_space(1))) void*)g,
      (__attribute__((address_space(3))) void*)l, 16, 0, 0);
}

// ---------------------------------------------------------------------------
// Fused gate + weight convert. Blocks [0, NT/4): gate (1 wave/token, double
// accum -> first-max argmax, bucket scatter, x->bf16). Blocks [NT/4, +8192):
// transpose-convert fp32 [E][K][N] -> bf16 [E][N][K] in 64n x 128k tiles
// (b64 LDS writes, 128B-segment global writes). Independent work; the gate
// hides under the convert in one dispatch.
// ---------------------------------------------------------------------------
__global__ __launch_bounds__(256) void gate_convert_kernel(
    const float* __restrict__ x, const float* __restrict__ gw,
    const float* __restrict__ gb, int* __restrict__ counts,
    int* __restrict__ bucket, __hip_bfloat16* __restrict__ xb,
    const float* __restrict__ w1, const float* __restrict__ w2,
    __hip_bfloat16* __restrict__ w1t, __hip_bfloat16* __restrict__ w2t) {
  __shared__ __align__(16) __hip_bfloat16 Ls[64][136];
  const int bid = blockIdx.x;
  const int tid = threadIdx.x;

  if (bid < NT / 4) {
    // ---- gate ----
    const int wid = tid >> 6;
    const int lane = tid & 63;
    const int t = bid * 4 + wid;

    const f4* xrow = (const f4*)(x + (size_t)t * DM);
    ushort4* xbrow = (ushort4*)(xb + (size_t)t * DM);

    double part[NE];
#pragma unroll
    for (int e = 0; e < NE; ++e) part[e] = 0.0;

#pragma unroll
    for (int q = 0; q < 4; ++q) {
      f4 v = xrow[q * 64 + lane];
      ushort4 s;
      s.x = f2bf(v[0]); s.y = f2bf(v[1]); s.z = f2bf(v[2]); s.w = f2bf(v[3]);
      xbrow[q * 64 + lane] = s;
#pragma unroll
      for (int e = 0; e < NE; ++e) {
        f4 w = ((const f4*)(gw + (size_t)e * DM))[q * 64 + lane];
        part[e] += (double)v[0] * w[0] + (double)v[1] * w[1] +
                   (double)v[2] * w[2] + (double)v[3] * w[3];
      }
    }
#pragma unroll
    for (int off = 32; off; off >>= 1) {
#pragma unroll
      for (int e = 0; e < NE; ++e) part[e] += __shfl_down(part[e], off);
    }
    if (lane == 0) {
      double best = part[0] + (double)gb[0];
      int bi = 0;
#pragma unroll
      for (int e = 1; e < NE; ++e) {
        double le = part[e] + (double)gb[e];
        if (le > best) { best = le; bi = e; }
      }
      int pos = atomicAdd(&counts[bi], 1);
      bucket[bi * NT + pos] = t;
    }
    return;
  }

  // ---- convert ----
  int id = bid - NT / 4;
  const float* S;
  __hip_bfloat16* D;
  int K, N, k0t, n0t;
  if (id < 4096) {  // w1: K=DM (8 k-tiles), N=DH (64 n-tiles)
    const int e = id >> 9, rem = id & 511;
    K = DM; N = DH;
    k0t = (rem >> 6) * 128; n0t = (rem & 63) * 64;
    S = w1 + (size_t)e * DM * DH;
    D = w1t + (size_t)e * DM * DH;
  } else {          // w2: K=DH (32 k-tiles), N=DM (16 n-tiles)
    id -= 4096;
    const int e = id >> 9, rem = id & 511;
    K = DH; N = DM;
    k0t = (rem >> 4) * 128; n0t = (rem & 15) * 64;
    S = w2 + (size_t)e * DH * DM;
    D = w2t + (size_t)e * DH * DM;
  }
  const int c = tid & 15, kq = tid >> 4;  // n-chunk, k-octet
  const float* src = S + (size_t)(k0t + kq * 8) * N + n0t + c * 4;
  f4 v[8];
#pragma unroll
  for (int j = 0; j < 8; ++j) v[j] = *(const f4*)(src + (size_t)j * N);
#pragma unroll
  for (int i = 0; i < 4; ++i) {
    ushort4 lo, hi;
    lo.x = f2bf(v[0][i]); lo.y = f2bf(v[1][i]);
    lo.z = f2bf(v[2][i]); lo.w = f2bf(v[3][i]);
    hi.x = f2bf(v[4][i]); hi.y = f2bf(v[5][i]);
    hi.z = f2bf(v[6][i]); hi.w = f2bf(v[7][i]);
    *(ushort4*)&Ls[c * 4 + i][kq * 8] = lo;
    *(ushort4*)&Ls[c * 4 + i][kq * 8 + 4] = hi;
  }
  __syncthreads();
  const int q = tid & 7, rn = tid >> 3;  // 8 x 16B = 128B row segments
#pragma unroll
  for (int p = 0; p < 2; ++p) {
    const int row = rn + 32 * p;
#pragma unroll
    for (int hh = 0; hh < 2; ++hh) {
      uint4 w = *(const uint4*)&Ls[row][q * 8 + hh * 64];
      *(uint4*)(D + (size_t)(n0t + row) * K + k0t + q * 8 + hh * 64) = w;
    }
  }
}

// ---------------------------------------------------------------------------
// Prefix + padded tile table + bucket padding.
// ---------------------------------------------------------------------------
__global__ void prefix_kernel(int* __restrict__ meta, int* __restrict__ bucket) {
  if (threadIdx.x == 0) {
    int r = 0, nt = 0;
    for (int e = 0; e < NE; ++e) {
      meta[MI_POFF + e] = r;
      const int cnt = meta[MI_COUNTS + e];
      const int T = (cnt + BM - 1) / BM;
      for (int j = 0; j < T; ++j) {
        meta[MI_TILEE + nt] = e;
        meta[MI_TILER + nt] = r + j * BM;
        meta[MI_TILES0 + nt] = j * BM;
        ++nt;
      }
      r += T * BM;
    }
    meta[MI_POFF + NE] = r;
    meta[MI_NTILES] = nt;
  }
  __syncthreads();
  for (int e = 0; e < NE; ++e) {
    const int cnt = meta[MI_COUNTS + e];
    if (cnt == 0) continue;
    const int padTo = ((cnt + BM - 1) / BM) * BM;
    const int last = bucket[e * NT + cnt - 1];
    for (int i = cnt + threadIdx.x; i < padTo; i += blockDim.x)
      bucket[e * NT + i] = last;
  }
}

// ---------------------------------------------------------------------------
// Uniform padded-tile routed GEMM: every block = one real 128x128 tile.
// 2-phase loop (STAGE next tile before COMPUTE, one barrier), gl_lds(16B).
// XCD-pinned decode: b&7 = XCD owns a contiguous N-panel range so each
// weight panel lives in exactly one XCD L2.
// MODE 0: A = xb gathered via padded bucket; out = relu(acc+b1) -> h rows.
// MODE 1: A = h rows; K-window kq*2048; out = fp32 partials P[kq].
// ---------------------------------------------------------------------------
template <int MODE>
__global__ __launch_bounds__(256, 2) void moe_gemm_u(
    const __hip_bfloat16* __restrict__ A, const __hip_bfloat16* __restrict__ B,
    const float* __restrict__ biasAll, const int* __restrict__ meta,
    const int* __restrict__ bucket, void* __restrict__ Out) {
  const int b = blockIdx.x;
  const int xcd = b & 7;
  const int idx = b >> 3;
  int tile, ntile, kq;
  if (MODE == 0) {
    const int grp = idx / MAXT;        // 0..3
    tile = idx - grp * MAXT;
    ntile = xcd * 4 + grp;             // 32 ntiles, 4 per XCD
    kq = 0;
  } else {
    const int grp = idx / MAXT;        // 0..1
    tile = idx - grp * MAXT;
    const int np = xcd * 2 + grp;      // 16 (ntile,kq) pairs, 2 per XCD
    ntile = np >> 1;
    kq = np & 1;
  }
  if (tile >= meta[MI_NTILES]) return;

  const int e = meta[MI_TILEE + tile];
  const int row0 = meta[MI_TILER + tile];
  const int s0 = meta[MI_TILES0 + tile];
  const int n0 = ntile * BN;
  const int Ktot = (MODE == 0) ? DM : DH;
  const int N = (MODE == 0) ? DH : DM;
  const int KTM = (MODE == 0) ? 32 : 64;
  const int kbase = (MODE == 0) ? 0 : kq * (DH / KSPL2);

  __shared__ __align__(16) __hip_bfloat16 As[2][BM][BK];
  __shared__ __align__(16) __hip_bfloat16 Bs[2][BN][BK];

  const int tid = threadIdx.x;
  const int lane = tid & 63;
  const int wid = tid >> 6;
  const int lr = lane >> 2, lc = lane & 3;  // 16 rows x 64 B per gl_lds inst

  const __hip_bfloat16 *aP0, *aP1;
  if (MODE == 0) {
    aP0 = A + (size_t)bucket[e * NT + s0 + 32 * wid + lr] * DM + lc * 8;
    aP1 = A + (size_t)bucket[e * NT + s0 + 32 * wid + 16 + lr] * DM + lc * 8;
  } else {
    aP0 = A + (size_t)(row0 + 32 * wid + lr) * DH + kbase + lc * 8;
    aP1 = A + (size_t)(row0 + 32 * wid + 16 + lr) * DH + kbase + lc * 8;
  }
  const __hip_bfloat16* bP0 =
      B + ((size_t)e * N + n0 + 32 * wid + lr) * Ktot + kbase + lc * 8;
  const __hip_bfloat16* bP1 = bP0 + (size_t)16 * Ktot;

  const int wm = (wid >> 1) * 64, wn = (wid & 1) * 64;
  const int fr = lane & 15, ks = lane >> 4;

  f32x4 acc[4][4];
#pragma unroll
  for (int m = 0; m < 4; ++m)
#pragma unroll
    for (int n = 0; n < 4; ++n) acc[m][n] = (f32x4){0.f, 0.f, 0.f, 0.f};

#define STAGE(bf, kt)                                  \
  do {                                                 \
    const size_t ko_ = (size_t)(kt) * BK;              \
    gload16(aP0 + ko_, &As[bf][32 * wid][0]);          \
    gload16(aP1 + ko_, &As[bf][32 * wid + 16][0]);     \
    gload16(bP0 + ko_, &Bs[bf][32 * wid][0]);          \
    gload16(bP1 + ko_, &Bs[bf][32 * wid + 16][0]);     \
  } while (0)

  STAGE(0, 0);
  __syncthreads();

  for (int kt = 0; kt < KTM; ++kt) {
    const int buf = kt & 1;
    if (kt + 1 < KTM) STAGE(buf ^ 1, kt + 1);  // loads fly under the MFMAs
    bf16x8 afr[4], bfr[4];
#pragma unroll
    for (int m = 0; m < 4; ++m)
      afr[m] = *(const bf16x8*)&As[buf][wm + m * 16 + fr][ks * 8];
#pragma unroll
    for (int n = 0; n < 4; ++n)
      bfr[n] = *(const bf16x8*)&Bs[buf][wn + n * 16 + fr][ks * 8];
#pragma unroll
    for (int m = 0; m < 4; ++m)
#pragma unroll
      for (int n = 0; n < 4; ++n)
        acc[m][n] = __builtin_amdgcn_mfma_f32_16x16x32_bf16(afr[m], bfr[n],
                                                            acc[m][n], 0, 0, 0);
    __syncthreads();
  }
#undef STAGE

  if (MODE == 0) {
    const float* bias = biasAll + (size_t)e * DH;
    __hip_bfloat16* Hout = (__hip_bfloat16*)Out;
#pragma unroll
    for (int m = 0; m < 4; ++m)
#pragma unroll
      for (int r = 0; r < 4; ++r) {
        const int row = wm + m * 16 + ks * 4 + r;
        __hip_bfloat16* orow = Hout + (size_t)(row0 + row) * DH;
#pragma unroll
        for (int n = 0; n < 4; ++n) {
          const int col = n0 + wn + n * 16 + fr;
          float v = acc[m][n][r] + bias[col];
          orow[col] = __float2bfloat16(v > 0.f ? v : 0.f);
        }
      }
  } else {
    float* Pout = (float*)Out + (size_t)kq * MAXROWS * DM;
#pragma unroll
    for (int m = 0; m < 4; ++m)
#pragma unroll
      for (int r = 0; r < 4; ++r) {
        const int row = wm + m * 16 + ks * 4 + r;
        float* orow = Pout + (size_t)(row0 + row) * DM;
#pragma unroll
        for (int n = 0; n < 4; ++n) {
          const int col = n0 + wn + n * 16 + fr;
          orow[col] = acc[m][n][r];
        }
      }
  }
}

// ---------------------------------------------------------------------------
// Reduce split-K partials, add b2, scatter padded-row -> token.
// ---------------------------------------------------------------------------
__global__ __launch_bounds__(256) void reduce_out_kernel(
    const float* __restrict__ P, const float* __restrict__ b2,
    const int* __restrict__ meta, const int* __restrict__ bucket,
    float* __restrict__ out) {
  const int gs = blockIdx.x;
  if (gs >= meta[MI_POFF + NE]) return;
  int e = 0;
#pragma unroll
  for (int i = 1; i < NE; ++i) e = (gs >= meta[MI_POFF + i]) ? i : e;
  const int i = gs - meta[MI_POFF + e];
  if (i >= meta[MI_COUNTS + e]) return;  // pad row
  const int tok = bucket[e * NT + i];
  const int c = threadIdx.x * 4;
  float4 v = *(const float4*)(P + (size_t)gs * DM + c);
#pragma unroll
  for (int q = 1; q < KSPL2; ++q) {
    float4 p = *(const float4*)(P + ((size_t)q * MAXROWS + gs) * DM + c);
    v.x += p.x; v.y += p.y; v.z += p.z; v.w += p.w;
  }
  float4 b = *(const float4*)(b2 + (size_t)e * DM + c);
  v.x += b.x; v.y += b.y; v.z += b.z; v.w += b.w;
  *(float4*)(out + (size_t)tok * DM + c) = v;
}

// ---------------------------------------------------------------------------
// Gate for fallback path (separate launch).
// ---------------------------------------------------------------------------
__global__ __launch_bounds__(256) void gate_route_kernel(
    const float* __restrict__ x, const float* __restrict__ gw,
    const float* __restrict__ gb, int* __restrict__ counts,
    int* __restrict__ bucket, __hip_bfloat16* __restrict__ xb) {
  const int wid = threadIdx.x >> 6;
  const int lane = threadIdx.x & 63;
  const int t = blockIdx.x * 4 + wid;

  const f4* xrow = (const f4*)(x + (size_t)t * DM);
  ushort4* xbrow = (ushort4*)(xb + (size_t)t * DM);

  double part[NE];
#pragma unroll
  for (int e = 0; e < NE; ++e) part[e] = 0.0;

#pragma unroll
  for (int q = 0; q < 4; ++q) {
    f4 v = xrow[q * 64 + lane];
    ushort4 s;
    s.x = f2bf(v[0]); s.y = f2bf(v[1]); s.z = f2bf(v[2]); s.w = f2bf(v[3]);
    xbrow[q * 64 + lane] = s;
#pragma unroll
    for (int e = 0; e < NE; ++e) {
      f4 w = ((const f4*)(gw + (size_t)e * DM))[q * 64 + lane];
      part[e] += (double)v[0] * w[0] + (double)v[1] * w[1] +
                 (double)v[2] * w[2] + (double)v[3] * w[3];
    }
  }
#pragma unroll
  for (int off = 32; off; off >>= 1) {
#pragma unroll
    for (int e = 0; e < NE; ++e) part[e] += __shfl_down(part[e], off);
  }
  if (lane == 0) {
    double best = part[0] + (double)gb[0];
    int bi = 0;
#pragma unroll
    for (int e = 1; e < NE; ++e) {
      double le = part[e] + (double)gb[e];
      if (le > best) { best = le; bi = e; }
    }
    int pos = atomicAdd(&counts[bi], 1);
    bucket[bi * NT + pos] = t;
  }
}

// ---------------------------------------------------------------------------
// Fallback for small ws (fp32-B fused, h in token order) — round-1 proven.
// ---------------------------------------------------------------------------
template <bool RELU_BF16>
__global__ __launch_bounds__(256, 2) void moe_gemm_fallback(
    const __hip_bfloat16* __restrict__ Aall, int lda,
    const float* __restrict__ Ball, int K, int N,
    const float* __restrict__ biasAll, const int* __restrict__ counts,
    const int* __restrict__ bucket, void* __restrict__ Out, int ldo) {
  const int e = blockIdx.z;
  const int cnt = counts[e];
  const int m0 = blockIdx.y * BM;
  if (m0 >= cnt) return;
  const int n0 = blockIdx.x * BN;

  const float* Bp = Ball + (size_t)e * K * N;
  const float* bias = biasAll + (size_t)e * N;
  const int* buck = bucket + e * NT;

  __shared__ __align__(16) __hip_bfloat16 As[2][BM][BKP];
  __shared__ __align__(16) __hip_bfloat16 Bs[2][BN][BKP];

  const int tid = threadIdx.x;
  const int lane = tid & 63;
  const int wid = tid >> 6;
  const int wm = (wid >> 1) * 64;
  const int wn = (wid & 1) * 64;
  const int fr = lane & 15;
  const int ks = lane >> 4;

  const int ar = tid >> 1;
  const int ah = tid & 1;
  const int atok = buck[min(m0 + ar, cnt - 1)];
  const __hip_bfloat16* aptr = Aall + (size_t)atok * lda + ah * 16;

  const int bc = tid & 31;
  const int bk0 = (tid >> 5) * 4;

  f32x4 acc[4][4];
#pragma unroll
  for (int m = 0; m < 4; ++m)
#pragma unroll
    for (int n = 0; n < 4; ++n) acc[m][n] = (f32x4){0.f, 0.f, 0.f, 0.f};

  const int KTf = K / BK;
  uint4 ra0, ra1;
  float rb[4][4];

  {
    const uint4* p = (const uint4*)(aptr);
    ra0 = p[0]; ra1 = p[1];
    const float* bbase = Bp + (size_t)bk0 * N + n0 + bc;
#pragma unroll
    for (int i = 0; i < 4; ++i)
#pragma unroll
      for (int j = 0; j < 4; ++j) rb[i][j] = bbase[(size_t)i * N + 32 * j];
  }
  {
    *(uint4*)&As[0][ar][ah * 16] = ra0;
    *(uint4*)&As[0][ar][ah * 16 + 8] = ra1;
#pragma unroll
    for (int j = 0; j < 4; ++j) {
      ushort4 w;
      w.x = f2bf(rb[0][j]); w.y = f2bf(rb[1][j]);
      w.z = f2bf(rb[2][j]); w.w = f2bf(rb[3][j]);
      *(ushort4*)&Bs[0][bc + 32 * j][bk0] = w;
    }
  }
  __syncthreads();

  for (int kt = 0; kt < KTf; ++kt) {
    const int buf = kt & 1;
    if (kt + 1 < KTf) {
      const uint4* p = (const uint4*)(aptr + (size_t)(kt + 1) * BK);
      ra0 = p[0]; ra1 = p[1];
      const float* bbase = Bp + (size_t)((kt + 1) * BK + bk0) * N + n0 + bc;
#pragma unroll
      for (int i = 0; i < 4; ++i)
#pragma unroll
        for (int j = 0; j < 4; ++j) rb[i][j] = bbase[(size_t)i * N + 32 * j];
    }

    bf16x8 afr[4], bfr[4];
#pragma unroll
    for (int m = 0; m < 4; ++m)
      afr[m] = *(const bf16x8*)&As[buf][wm + m * 16 + fr][ks * 8];
#pragma unroll
    for (int n = 0; n < 4; ++n)
      bfr[n] = *(const bf16x8*)&Bs[buf][wn + n * 16 + fr][ks * 8];
#pragma unroll
    for (int m = 0; m < 4; ++m)
#pragma unroll
      for (int n = 0; n < 4; ++n)
        acc[m][n] = __builtin_amdgcn_mfma_f32_16x16x32_bf16(afr[m], bfr[n],
                                                            acc[m][n], 0, 0, 0);

    __syncthreads();
    if (kt + 1 < KTf) {
      *(uint4*)&As[buf ^ 1][ar][ah * 16] = ra0;
      *(uint4*)&As[buf ^ 1][ar][ah * 16 + 8] = ra1;
#pragma unroll
      for (int j = 0; j < 4; ++j) {
        ushort4 w;
        w.x = f2bf(rb[0][j]); w.y = f2bf(rb[1][j]);
        w.z = f2bf(rb[2][j]); w.w = f2bf(rb[3][j]);
        *(ushort4*)&Bs[buf ^ 1][bc + 32 * j][bk0] = w;
      }
      __syncthreads();
    }
  }

  float* outF = (float*)Out;
  __hip_bfloat16* outB = (__hip_bfloat16*)Out;
#pragma unroll
  for (int m = 0; m < 4; ++m) {
#pragma unroll
    for (int r = 0; r < 4; ++r) {
      const int row = wm + m * 16 + ks * 4 + r;
      const int slot = m0 + row;
      if (slot < cnt) {
        const int tok = buck[slot];
#pragma unroll
        for (int n = 0; n < 4; ++n) {
          const int col = n0 + wn + n * 16 + fr;
          float v = acc[m][n][r] + bias[col];
          if (RELU_BF16) {
            v = v > 0.f ? v : 0.f;
            outB[(size_t)tok * ldo + col] = __float2bfloat16(v);
          } else {
            outF[(size_t)tok * ldo + col] = v;
          }
        }
      }
    }
  }
}

extern "C" void kernel_launch(void* const* d_in, const int* in_sizes, int n_in,
                              void* d_out, int out_size, void* d_ws,
                              size_t ws_size, hipStream_t stream) {
  const float* x = (const float*)d_in[0];
  const float* gw = (const float*)d_in[1];
  const float* gb = (const float*)d_in[2];
  const float* w1 = (const float*)d_in[3];
  const float* b1 = (const float*)d_in[4];
  const float* w2 = (const float*)d_in[5];
  const float* b2 = (const float*)d_in[6];
  (void)in_sizes; (void)n_in; (void)out_size;

  char* ws = (char*)d_ws;
  int* meta = (int*)ws;
  int* counts = meta + MI_COUNTS;
  int* bucket = (int*)(ws + O_BUCKET);
  __hip_bfloat16* xb = (__hip_bfloat16*)(ws + O_XB);
  __hip_bfloat16* h = (__hip_bfloat16*)(ws + O_H);

  hipMemsetAsync(ws, 0, 1024, stream);

  if (ws_size >= WS_NEED) {
    __hip_bfloat16* w1t = (__hip_bfloat16*)(ws + O_W1T);
    __hip_bfloat16* w2t = (__hip_bfloat16*)(ws + O_W2T);
    float* P = (float*)(ws + O_P);

    gate_convert_kernel<<<NT / 4 + 8192, 256, 0, stream>>>(
        x, gw, gb, counts, bucket, xb, w1, w2, w1t, w2t);
    prefix_kernel<<<1, 256, 0, stream>>>(meta, bucket);
    moe_gemm_u<0><<<8 * 4 * MAXT, 256, 0, stream>>>(
        xb, w1t, b1, meta, bucket, (void*)h);
    moe_gemm_u<1><<<8 * 2 * MAXT, 256, 0, stream>>>(
        h, w2t, nullptr, meta, bucket, (void*)P);
    reduce_out_kernel<<<MAXROWS, 256, 0, stream>>>(P, b2, meta, bucket,
                                                   (float*)d_out);
  } else {
    gate_route_kernel<<<NT / 4, 256, 0, stream>>>(x, gw, gb, counts, bucket,
                                                  xb);
    dim3 g1(DH / BN, NT / BM, NE);
    moe_gemm_fallback<true><<<g1, 256, 0, stream>>>(
        xb, DM, w1, DM, DH, b1, counts, bucket, (void*)h, DH);
    dim3 g2(DM / BN, NT / BM, NE);
    moe_gemm_fallback<false><<<g2, 256, 0, stream>>>(
        h, DH, w2, DH, DM, b2, counts, bucket, d_out, DM);
  }
}

// Round 8
// 266.530 us; speedup vs baseline: 1.3875x; 1.0534x over previous
//
#include <hip/hip_runtime.h>
#include <hip/hip_bf16.h>

#define NT 4096   // tokens
#define DM 1024   // d_model
#define DH 4096   // d_hidden
#define NE 8      // experts

#define BM 128
#define BN 128
#define BK 32
#define MAXT 40      // max padded M-tiles (worst skew: 32 + 7 = 39)
#define MAXROWS 5120 // 40*128
#define KSPL2 2      // split-K for GEMM2 (K-window 2048)
#define BKP 40       // fallback LDS pad
#define G1B (8 * 4 * MAXT)  // gemm1 block count (1280)

typedef short bf16x8 __attribute__((ext_vector_type(8)));
typedef float f32x4 __attribute__((ext_vector_type(4)));
typedef float f4 __attribute__((ext_vector_type(4)));
typedef unsigned short u16x8 __attribute__((ext_vector_type(8)));

// meta ints at ws base
#define MI_COUNTS 0
#define MI_POFF   16
#define MI_NTILES 32
#define MI_TILEE  48
#define MI_TILER  112
#define MI_TILES0 176

#define O_BUCKET 1024ull
#define O_XB  (O_BUCKET + (size_t)NE * NT * 4)
#define O_H   (O_XB + (size_t)NT * DM * 2)                     // +8 MB
#define O_W1T (O_H + (size_t)MAXROWS * DH * 2)                 // +40 MB
#define O_W2T (O_W1T + (size_t)NE * DM * DH * 2)               // +64 MB
#define WS_NEED (O_W2T + (size_t)NE * DH * DM * 2)             // ~176 MiB
#define O_P   O_W1T   // split-K partials (2*MAXROWS*DM*4 = 40MB) alias w1t

static __device__ __forceinline__ unsigned short f2bf(float f) {
  union { __hip_bfloat16 h; unsigned short u; } cv;
  cv.h = __float2bfloat16(f);
  return cv.u;
}

static __device__ __forceinline__ void gload16(const void* g, void* l) {
  __builtin_amdgcn_global_load_lds(
      (const __attribute__((address_space(1))) void*)g,
      (__attribute__((address_space(3))) void*)l, 16, 0, 0);
}

// ---------------------------------------------------------------------------
// Transpose-convert one 128k x 64n tile: src [K][N] fp32 -> dst [N][K] bf16.
// Phase 1: thread (c=tid&15, kq=tid>>4) reads 8 rows x f4, writes 4 x 16B
// u16x8 into Ls (row stride 136 elem = 272 B -> 16B writes cover all 32
// banks evenly). Phase 2: 4 threads/row write 256 B/row coalesced.
// ---------------------------------------------------------------------------
static __device__ __forceinline__ void convert_tile(
    const float* __restrict__ S, __hip_bfloat16* __restrict__ D, int K, int N,
    int k0, int n0, char* smem) {
  auto Ls = reinterpret_cast<__hip_bfloat16(*)[136]>(smem);
  const int tid = threadIdx.x;
  const int c = tid & 15, kq = tid >> 4;
  const float* src = S + (size_t)(k0 + kq * 8) * N + n0 + c * 4;
  f4 v[8];
#pragma unroll
  for (int j = 0; j < 8; ++j) v[j] = *(const f4*)(src + (size_t)j * N);
#pragma unroll
  for (int i = 0; i < 4; ++i) {
    u16x8 w;
#pragma unroll
    for (int j = 0; j < 8; ++j) w[j] = f2bf(v[j][i]);
    *(u16x8*)&Ls[c * 4 + i][kq * 8] = w;
  }
  __syncthreads();
  const int r = tid >> 2, q = tid & 3;
  __hip_bfloat16* drow = D + (size_t)(n0 + r) * K + k0 + q * 32;
#pragma unroll
  for (int u = 0; u < 4; ++u) {
    uint4 w = *(const uint4*)&Ls[r][q * 32 + u * 8];
    *(uint4*)(drow + u * 8) = w;
  }
}

// ---------------------------------------------------------------------------
// Gate wave body: 8 logits (double accum -> first-max argmax), bucket
// scatter, x -> bf16.
// ---------------------------------------------------------------------------
static __device__ __forceinline__ void gate_body(
    const float* __restrict__ x, const float* __restrict__ gw,
    const float* __restrict__ gb, int* __restrict__ counts,
    int* __restrict__ bucket, __hip_bfloat16* __restrict__ xb, int bid) {
  const int tid = threadIdx.x;
  const int wid = tid >> 6;
  const int lane = tid & 63;
  const int t = bid * 4 + wid;

  const f4* xrow = (const f4*)(x + (size_t)t * DM);
  ushort4* xbrow = (ushort4*)(xb + (size_t)t * DM);

  double part[NE];
#pragma unroll
  for (int e = 0; e < NE; ++e) part[e] = 0.0;

#pragma unroll
  for (int q = 0; q < 4; ++q) {
    f4 v = xrow[q * 64 + lane];
    ushort4 s;
    s.x = f2bf(v[0]); s.y = f2bf(v[1]); s.z = f2bf(v[2]); s.w = f2bf(v[3]);
    xbrow[q * 64 + lane] = s;
#pragma unroll
    for (int e = 0; e < NE; ++e) {
      f4 w = ((const f4*)(gw + (size_t)e * DM))[q * 64 + lane];
      part[e] += (double)v[0] * w[0] + (double)v[1] * w[1] +
                 (double)v[2] * w[2] + (double)v[3] * w[3];
    }
  }
#pragma unroll
  for (int off = 32; off; off >>= 1) {
#pragma unroll
    for (int e = 0; e < NE; ++e) part[e] += __shfl_down(part[e], off);
  }
  if (lane == 0) {
    double best = part[0] + (double)gb[0];
    int bi = 0;
#pragma unroll
    for (int e = 1; e < NE; ++e) {
      double le = part[e] + (double)gb[e];
      if (le > best) { best = le; bi = e; }
    }
    int pos = atomicAdd(&counts[bi], 1);
    bucket[bi * NT + pos] = t;
  }
}

// ---------------------------------------------------------------------------
// Kernel 1: gate (blocks 0..1023) + convert w1 (blocks 1024..5119).
// Both depend only on inputs -> run concurrently in one dispatch.
// ---------------------------------------------------------------------------
__global__ __launch_bounds__(256) void gate_cw1_kernel(
    const float* __restrict__ x, const float* __restrict__ gw,
    const float* __restrict__ gb, int* __restrict__ counts,
    int* __restrict__ bucket, __hip_bfloat16* __restrict__ xb,
    const float* __restrict__ w1, __hip_bfloat16* __restrict__ w1t) {
  __shared__ __align__(16) char smem[17408];
  const int bid = blockIdx.x;
  if (bid < NT / 4) {
    gate_body(x, gw, gb, counts, bucket, xb, bid);
    return;
  }
  const int id = bid - NT / 4;
  const int e = id >> 9, rem = id & 511;
  convert_tile(w1 + (size_t)e * DM * DH, w1t + (size_t)e * DM * DH, DM, DH,
               (rem >> 6) * 128, (rem & 63) * 64, smem);
}

// ---------------------------------------------------------------------------
// Prefix + padded tile table + bucket padding.
// ---------------------------------------------------------------------------
__global__ void prefix_kernel(int* __restrict__ meta, int* __restrict__ bucket) {
  if (threadIdx.x == 0) {
    int r = 0, nt = 0;
    for (int e = 0; e < NE; ++e) {
      meta[MI_POFF + e] = r;
      const int cnt = meta[MI_COUNTS + e];
      const int T = (cnt + BM - 1) / BM;
      for (int j = 0; j < T; ++j) {
        meta[MI_TILEE + nt] = e;
        meta[MI_TILER + nt] = r + j * BM;
        meta[MI_TILES0 + nt] = j * BM;
        ++nt;
      }
      r += T * BM;
    }
    meta[MI_POFF + NE] = r;
    meta[MI_NTILES] = nt;
  }
  __syncthreads();
  for (int e = 0; e < NE; ++e) {
    const int cnt = meta[MI_COUNTS + e];
    if (cnt == 0) continue;
    const int padTo = ((cnt + BM - 1) / BM) * BM;
    const int last = bucket[e * NT + cnt - 1];
    for (int i = cnt + threadIdx.x; i < padTo; i += blockDim.x)
      bucket[e * NT + i] = last;
  }
}

// ---------------------------------------------------------------------------
// GEMM body (round-7 proven): 128x128 tile, 2-phase gl_lds double buffer,
// XCD-pinned decode. MODE 0 -> relu(+b1) bf16 h; MODE 1 -> fp32 partials.
// ---------------------------------------------------------------------------
template <int MODE>
static __device__ __forceinline__ void gemm_body(
    char* smem, int b, const __hip_bfloat16* __restrict__ A,
    const __hip_bfloat16* __restrict__ B, const float* __restrict__ biasAll,
    const int* __restrict__ meta, const int* __restrict__ bucket,
    void* __restrict__ Out) {
  auto As = reinterpret_cast<__hip_bfloat16(*)[BM][BK]>(smem);
  auto Bs = reinterpret_cast<__hip_bfloat16(*)[BN][BK]>(smem + 16384);

  const int xcd = b & 7;
  const int idx = b >> 3;
  int tile, ntile, kq;
  if (MODE == 0) {
    const int grp = idx / MAXT;        // 0..3
    tile = idx - grp * MAXT;
    ntile = xcd * 4 + grp;             // 32 ntiles, 4 per XCD
    kq = 0;
  } else {
    const int grp = idx / MAXT;        // 0..1
    tile = idx - grp * MAXT;
    const int np = xcd * 2 + grp;      // 16 (ntile,kq) pairs, 2 per XCD
    ntile = np >> 1;
    kq = np & 1;
  }
  if (tile >= meta[MI_NTILES]) return;

  const int e = meta[MI_TILEE + tile];
  const int row0 = meta[MI_TILER + tile];
  const int s0 = meta[MI_TILES0 + tile];
  const int n0 = ntile * BN;
  const int Ktot = (MODE == 0) ? DM : DH;
  const int N = (MODE == 0) ? DH : DM;
  const int KTM = (MODE == 0) ? 32 : 64;
  const int kbase = (MODE == 0) ? 0 : kq * (DH / KSPL2);

  const int tid = threadIdx.x;
  const int lane = tid & 63;
  const int wid = tid >> 6;
  const int lr = lane >> 2, lc = lane & 3;

  const __hip_bfloat16 *aP0, *aP1;
  if (MODE == 0) {
    aP0 = A + (size_t)bucket[e * NT + s0 + 32 * wid + lr] * DM + lc * 8;
    aP1 = A + (size_t)bucket[e * NT + s0 + 32 * wid + 16 + lr] * DM + lc * 8;
  } else {
    aP0 = A + (size_t)(row0 + 32 * wid + lr) * DH + kbase + lc * 8;
    aP1 = A + (size_t)(row0 + 32 * wid + 16 + lr) * DH + kbase + lc * 8;
  }
  const __hip_bfloat16* bP0 =
      B + ((size_t)e * N + n0 + 32 * wid + lr) * Ktot + kbase + lc * 8;
  const __hip_bfloat16* bP1 = bP0 + (size_t)16 * Ktot;

  const int wm = (wid >> 1) * 64, wn = (wid & 1) * 64;
  const int fr = lane & 15, ks = lane >> 4;

  f32x4 acc[4][4];
#pragma unroll
  for (int m = 0; m < 4; ++m)
#pragma unroll
    for (int n = 0; n < 4; ++n) acc[m][n] = (f32x4){0.f, 0.f, 0.f, 0.f};

#define STAGE(bf, kt)                                  \
  do {                                                 \
    const size_t ko_ = (size_t)(kt) * BK;              \
    gload16(aP0 + ko_, &As[bf][32 * wid][0]);          \
    gload16(aP1 + ko_, &As[bf][32 * wid + 16][0]);     \
    gload16(bP0 + ko_, &Bs[bf][32 * wid][0]);          \
    gload16(bP1 + ko_, &Bs[bf][32 * wid + 16][0]);     \
  } while (0)

  STAGE(0, 0);
  __syncthreads();

  for (int kt = 0; kt < KTM; ++kt) {
    const int buf = kt & 1;
    if (kt + 1 < KTM) STAGE(buf ^ 1, kt + 1);  // loads fly under the MFMAs
    bf16x8 afr[4], bfr[4];
#pragma unroll
    for (int m = 0; m < 4; ++m)
      afr[m] = *(const bf16x8*)&As[buf][wm + m * 16 + fr][ks * 8];
#pragma unroll
    for (int n = 0; n < 4; ++n)
      bfr[n] = *(const bf16x8*)&Bs[buf][wn + n * 16 + fr][ks * 8];
#pragma unroll
    for (int m = 0; m < 4; ++m)
#pragma unroll
      for (int n = 0; n < 4; ++n)
        acc[m][n] = __builtin_amdgcn_mfma_f32_16x16x32_bf16(afr[m], bfr[n],
                                                            acc[m][n], 0, 0, 0);
    __syncthreads();
  }
#undef STAGE

  if (MODE == 0) {
    const float* bias = biasAll + (size_t)e * DH;
    __hip_bfloat16* Hout = (__hip_bfloat16*)Out;
#pragma unroll
    for (int m = 0; m < 4; ++m)
#pragma unroll
      for (int r = 0; r < 4; ++r) {
        const int row = wm + m * 16 + ks * 4 + r;
        __hip_bfloat16* orow = Hout + (size_t)(row0 + row) * DH;
#pragma unroll
        for (int n = 0; n < 4; ++n) {
          const int col = n0 + wn + n * 16 + fr;
          float v = acc[m][n][r] + bias[col];
          orow[col] = __float2bfloat16(v > 0.f ? v : 0.f);
        }
      }
  } else {
    float* Pout = (float*)Out + (size_t)kq * MAXROWS * DM;
#pragma unroll
    for (int m = 0; m < 4; ++m)
#pragma unroll
      for (int r = 0; r < 4; ++r) {
        const int row = wm + m * 16 + ks * 4 + r;
        float* orow = Pout + (size_t)(row0 + row) * DM;
#pragma unroll
        for (int n = 0; n < 4; ++n) {
          const int col = n0 + wn + n * 16 + fr;
          orow[col] = acc[m][n][r];
        }
      }
  }
}

// ---------------------------------------------------------------------------
// Kernel 3: gemm1 (blocks 0..G1B-1) + convert w2 (blocks G1B..G1B+4095).
// gemm1 consumes w1t/bucket; cw2 only reads w2 -> independent, overlapped.
// ---------------------------------------------------------------------------
__global__ __launch_bounds__(256, 2) void gemm1_cw2_kernel(
    const __hip_bfloat16* __restrict__ xb, const __hip_bfloat16* __restrict__ w1t,
    const float* __restrict__ b1, const int* __restrict__ meta,
    const int* __restrict__ bucket, __hip_bfloat16* __restrict__ h,
    const float* __restrict__ w2, __hip_bfloat16* __restrict__ w2t) {
  __shared__ __align__(16) char smem[32768];
  const int bid = blockIdx.x;
  if (bid < G1B) {
    gemm_body<0>(smem, bid, xb, w1t, b1, meta, bucket, (void*)h);
    return;
  }
  const int id = bid - G1B;
  const int e = id >> 9, rem = id & 511;
  convert_tile(w2 + (size_t)e * DH * DM, w2t + (size_t)e * DH * DM, DH, DM,
               (rem >> 4) * 128, (rem & 15) * 64, smem);
}

// ---------------------------------------------------------------------------
// Kernel 4: gemm2 (split-K=2).
// ---------------------------------------------------------------------------
__global__ __launch_bounds__(256, 2) void gemm2_kernel(
    const __hip_bfloat16* __restrict__ h, const __hip_bfloat16* __restrict__ w2t,
    const int* __restrict__ meta, const int* __restrict__ bucket,
    float* __restrict__ P) {
  __shared__ __align__(16) char smem[32768];
  gemm_body<1>(smem, blockIdx.x, h, w2t, nullptr, meta, bucket, (void*)P);
}

// ---------------------------------------------------------------------------
// Reduce split-K partials, add b2, scatter padded-row -> token.
// ---------------------------------------------------------------------------
__global__ __launch_bounds__(256) void reduce_out_kernel(
    const float* __restrict__ P, const float* __restrict__ b2,
    const int* __restrict__ meta, const int* __restrict__ bucket,
    float* __restrict__ out) {
  const int gs = blockIdx.x;
  if (gs >= meta[MI_POFF + NE]) return;
  int e = 0;
#pragma unroll
  for (int i = 1; i < NE; ++i) e = (gs >= meta[MI_POFF + i]) ? i : e;
  const int i = gs - meta[MI_POFF + e];
  if (i >= meta[MI_COUNTS + e]) return;  // pad row
  const int tok = bucket[e * NT + i];
  const int c = threadIdx.x * 4;
  float4 v = *(const float4*)(P + (size_t)gs * DM + c);
#pragma unroll
  for (int q = 1; q < KSPL2; ++q) {
    float4 p = *(const float4*)(P + ((size_t)q * MAXROWS + gs) * DM + c);
    v.x += p.x; v.y += p.y; v.z += p.z; v.w += p.w;
  }
  float4 b = *(const float4*)(b2 + (size_t)e * DM + c);
  v.x += b.x; v.y += b.y; v.z += b.z; v.w += b.w;
  *(float4*)(out + (size_t)tok * DM + c) = v;
}

// ---------------------------------------------------------------------------
// Fallback path (small ws): round-1 proven kernels.
// ---------------------------------------------------------------------------
__global__ __launch_bounds__(256) void gate_route_kernel(
    const float* __restrict__ x, const float* __restrict__ gw,
    const float* __restrict__ gb, int* __restrict__ counts,
    int* __restrict__ bucket, __hip_bfloat16* __restrict__ xb) {
  gate_body(x, gw, gb, counts, bucket, xb, blockIdx.x);
}

template <bool RELU_BF16>
__global__ __launch_bounds__(256, 2) void moe_gemm_fallback(
    const __hip_bfloat16* __restrict__ Aall, int lda,
    const float* __restrict__ Ball, int K, int N,
    const float* __restrict__ biasAll, const int* __restrict__ counts,
    const int* __restrict__ bucket, void* __restrict__ Out, int ldo) {
  const int e = blockIdx.z;
  const int cnt = counts[e];
  const int m0 = blockIdx.y * BM;
  if (m0 >= cnt) return;
  const int n0 = blockIdx.x * BN;

  const float* Bp = Ball + (size_t)e * K * N;
  const float* bias = biasAll + (size_t)e * N;
  const int* buck = bucket + e * NT;

  __shared__ __align__(16) __hip_bfloat16 As[2][BM][BKP];
  __shared__ __align__(16) __hip_bfloat16 Bs[2][BN][BKP];

  const int tid = threadIdx.x;
  const int lane = tid & 63;
  const int wid = tid >> 6;
  const int wm = (wid >> 1) * 64;
  const int wn = (wid & 1) * 64;
  const int fr = lane & 15;
  const int ks = lane >> 4;

  const int ar = tid >> 1;
  const int ah = tid & 1;
  const int atok = buck[min(m0 + ar, cnt - 1)];
  const __hip_bfloat16* aptr = Aall + (size_t)atok * lda + ah * 16;

  const int bc = tid & 31;
  const int bk0 = (tid >> 5) * 4;

  f32x4 acc[4][4];
#pragma unroll
  for (int m = 0; m < 4; ++m)
#pragma unroll
    for (int n = 0; n < 4; ++n) acc[m][n] = (f32x4){0.f, 0.f, 0.f, 0.f};

  const int KTf = K / BK;
  uint4 ra0, ra1;
  float rb[4][4];

  {
    const uint4* p = (const uint4*)(aptr);
    ra0 = p[0]; ra1 = p[1];
    const float* bbase = Bp + (size_t)bk0 * N + n0 + bc;
#pragma unroll
    for (int i = 0; i < 4; ++i)
#pragma unroll
      for (int j = 0; j < 4; ++j) rb[i][j] = bbase[(size_t)i * N + 32 * j];
  }
  {
    *(uint4*)&As[0][ar][ah * 16] = ra0;
    *(uint4*)&As[0][ar][ah * 16 + 8] = ra1;
#pragma unroll
    for (int j = 0; j < 4; ++j) {
      ushort4 w;
      w.x = f2bf(rb[0][j]); w.y = f2bf(rb[1][j]);
      w.z = f2bf(rb[2][j]); w.w = f2bf(rb[3][j]);
      *(ushort4*)&Bs[0][bc + 32 * j][bk0] = w;
    }
  }
  __syncthreads();

  for (int kt = 0; kt < KTf; ++kt) {
    const int buf = kt & 1;
    if (kt + 1 < KTf) {
      const uint4* p = (const uint4*)(aptr + (size_t)(kt + 1) * BK);
      ra0 = p[0]; ra1 = p[1];
      const float* bbase = Bp + (size_t)((kt + 1) * BK + bk0) * N + n0 + bc;
#pragma unroll
      for (int i = 0; i < 4; ++i)
#pragma unroll
        for (int j = 0; j < 4; ++j) rb[i][j] = bbase[(size_t)i * N + 32 * j];
    }

    bf16x8 afr[4], bfr[4];
#pragma unroll
    for (int m = 0; m < 4; ++m)
      afr[m] = *(const bf16x8*)&As[buf][wm + m * 16 + fr][ks * 8];
#pragma unroll
    for (int n = 0; n < 4; ++n)
      bfr[n] = *(const bf16x8*)&Bs[buf][wn + n * 16 + fr][ks * 8];
#pragma unroll
    for (int m = 0; m < 4; ++m)
#pragma unroll
      for (int n = 0; n < 4; ++n)
        acc[m][n] = __builtin_amdgcn_mfma_f32_16x16x32_bf16(afr[m], bfr[n],
                                                            acc[m][n], 0, 0, 0);

    __syncthreads();
    if (kt + 1 < KTf) {
      *(uint4*)&As[buf ^ 1][ar][ah * 16] = ra0;
      *(uint4*)&As[buf ^ 1][ar][ah * 16 + 8] = ra1;
#pragma unroll
      for (int j = 0; j < 4; ++j) {
        ushort4 w;
        w.x = f2bf(rb[0][j]); w.y = f2bf(rb[1][j]);
        w.z = f2bf(rb[2][j]); w.w = f2bf(rb[3][j]);
        *(ushort4*)&Bs[buf ^ 1][bc + 32 * j][bk0] = w;
      }
      __syncthreads();
    }
  }

  float* outF = (float*)Out;
  __hip_bfloat16* outB = (__hip_bfloat16*)Out;
#pragma unroll
  for (int m = 0; m < 4; ++m) {
#pragma unroll
    for (int r = 0; r < 4; ++r) {
      const int row = wm + m * 16 + ks * 4 + r;
      const int slot = m0 + row;
      if (slot < cnt) {
        const int tok = buck[slot];
#pragma unroll
        for (int n = 0; n < 4; ++n) {
          const int col = n0 + wn + n * 16 + fr;
          float v = acc[m][n][r] + bias[col];
          if (RELU_BF16) {
            v = v > 0.f ? v : 0.f;
            outB[(size_t)tok * ldo + col] = __float2bfloat16(v);
          } else {
            outF[(size_t)tok * ldo + col] = v;
          }
        }
      }
    }
  }
}

extern "C" void kernel_launch(void* const* d_in, const int* in_sizes, int n_in,
                              void* d_out, int out_size, void* d_ws,
                              size_t ws_size, hipStream_t stream) {
  const float* x = (const float*)d_in[0];
  const float* gw = (const float*)d_in[1];
  const float* gb = (const float*)d_in[2];
  const float* w1 = (const float*)d_in[3];
  const float* b1 = (const float*)d_in[4];
  const float* w2 = (const float*)d_in[5];
  const float* b2 = (const float*)d_in[6];
  (void)in_sizes; (void)n_in; (void)out_size;

  char* ws = (char*)d_ws;
  int* meta = (int*)ws;
  int* counts = meta + MI_COUNTS;
  int* bucket = (int*)(ws + O_BUCKET);
  __hip_bfloat16* xb = (__hip_bfloat16*)(ws + O_XB);
  __hip_bfloat16* h = (__hip_bfloat16*)(ws + O_H);

  hipMemsetAsync(ws, 0, 1024, stream);

  if (ws_size >= WS_NEED) {
    __hip_bfloat16* w1t = (__hip_bfloat16*)(ws + O_W1T);
    __hip_bfloat16* w2t = (__hip_bfloat16*)(ws + O_W2T);
    float* P = (float*)(ws + O_P);

    gate_cw1_kernel<<<NT / 4 + 4096, 256, 0, stream>>>(
        x, gw, gb, counts, bucket, xb, w1, w1t);
    prefix_kernel<<<1, 256, 0, stream>>>(meta, bucket);
    gemm1_cw2_kernel<<<G1B + 4096, 256, 0, stream>>>(
        xb, w1t, b1, meta, bucket, h, w2, w2t);
    gemm2_kernel<<<8 * 2 * MAXT, 256, 0, stream>>>(h, w2t, meta, bucket, P);
    reduce_out_kernel<<<MAXROWS, 256, 0, stream>>>(P, b2, meta, bucket,
                                                   (float*)d_out);
  } else {
    gate_route_kernel<<<NT / 4, 256, 0, stream>>>(x, gw, gb, counts, bucket,
                                                  xb);
    dim3 g1(DH / BN, NT / BM, NE);
    moe_gemm_fallback<true><<<g1, 256, 0, stream>>>(
        xb, DM, w1, DM, DH, b1, counts, bucket, (void*)h, DH);
    dim3 g2(DM / BN, NT / BM, NE);
    moe_gemm_fallback<false><<<g2, 256, 0, stream>>>(
        h, DH, w2, DH, DM, b2, counts, bucket, d_out, DM);
  }
}